// Round 2
// baseline (497.666 us; speedup 1.0000x reference)
//
#include <hip/hip_runtime.h>
#include <math.h>

// Problem constants
#define BB   2
#define SS   1024
#define HH   4096
#define NHH  32
#define NKVV 8
#define HDD  128
#define MR   2048   // B*S
#define KVD  1024   // NKV*HD
#define NQKVD 6144  // H + 2*KVD
#define KD   4096
#define KHALF 2048
#define SCALE_F 0.08838834764831845f  // 1/sqrt(128)

typedef __attribute__((ext_vector_type(8))) short bf16x8;
typedef __attribute__((ext_vector_type(4))) float f32x4;
typedef __attribute__((ext_vector_type(4))) int i32x4;

#define MFMA(a, b, c) __builtin_amdgcn_mfma_f32_16x16x32_bf16((a), (b), (c), 0, 0, 0)
#define MFMA_I8(a, b, c) __builtin_amdgcn_mfma_i32_16x16x64_i8((a), (b), (c), 0, 0, 0)

__device__ __forceinline__ unsigned short f2bf(float f) {
  union { float f; unsigned u; } v; v.f = f;
  return (unsigned short)((v.u + 0x7fffu + ((v.u >> 16) & 1u)) >> 16);
}
__device__ __forceinline__ unsigned short f2h(float f) {
  union { _Float16 h; unsigned short s; } v; v.h = (_Float16)f; return v.s;
}
__device__ __forceinline__ float h2f(unsigned short s) {
  union { unsigned short s; _Float16 h; } v; v.s = s; return (float)v.h;
}
__device__ __forceinline__ float bf2f(unsigned short s) {
  union { unsigned u; float f; } v; v.u = ((unsigned)s) << 16; return v.f;
}
__device__ __forceinline__ float4 ld4h(const unsigned short* p) {
  uint2 d = *(const uint2*)p;
  float4 r;
  r.x = h2f((unsigned short)(d.x & 0xffff)); r.y = h2f((unsigned short)(d.x >> 16));
  r.z = h2f((unsigned short)(d.y & 0xffff)); r.w = h2f((unsigned short)(d.y >> 16));
  return r;
}

__device__ __forceinline__ void gload_lds16(const void* g, void* l) {
  __builtin_amdgcn_global_load_lds(
      (const __attribute__((address_space(1))) void*)g,
      (__attribute__((address_space(3))) void*)l, 16, 0, 0);
}

__device__ __forceinline__ signed char q8(float x, float inv) {
  float r = rintf(x * inv);
  r = fmaxf(-127.f, fminf(127.f, r));
  return (signed char)(int)r;
}

// ---------------- fused weight conversion: all 4 matrices, int32 -> int8 ----------------
#define NQ16 ((size_t)HH * HH / 16)
#define NK16 ((size_t)KVD * HH / 16)
__global__ void cvt_w_all(const int* __restrict__ wq, const int* __restrict__ wk,
                          const int* __restrict__ wv, const int* __restrict__ wo,
                          signed char* __restrict__ wqkv, signed char* __restrict__ wo8) {
  size_t i = (size_t)blockIdx.x * 256 + threadIdx.x;  // 16-elem chunk id
  const int* src;
  signed char* dst;
  if (i < NQ16) { src = wq; dst = wqkv; }
  else if (i < NQ16 + NK16) { src = wk - NQ16 * 16; dst = wqkv; }
  else if (i < NQ16 + 2 * NK16) { src = wv - (NQ16 + NK16) * 16; dst = wqkv; }
  else { src = wo - (NQ16 + 2 * NK16) * 16; dst = wo8 - (NQ16 + 2 * NK16) * 16; }
  const int4* p = (const int4*)(src + i * 16);
  union { signed char c[16]; int4 q; } o;
#pragma unroll
  for (int j = 0; j < 4; ++j) {
    int4 v = p[j];
    o.c[j * 4 + 0] = (signed char)v.x; o.c[j * 4 + 1] = (signed char)v.y;
    o.c[j * 4 + 2] = (signed char)v.z; o.c[j * 4 + 3] = (signed char)v.w;
  }
  *(int4*)(dst + i * 16) = o.q;
}

// ---------------- per-row quantization: one 256-thread block per row of 4096 ----------------
__global__ void quant_f32(const float* __restrict__ in, signed char* __restrict__ out,
                          float* __restrict__ scale) {
  __shared__ float wm[4];
  const int row = blockIdx.x;
  const int t = threadIdx.x;
  const float4* p = (const float4*)(in + (size_t)row * HH) + t * 4;
  float4 v[4];
  float m = 0.f;
#pragma unroll
  for (int j = 0; j < 4; ++j) {
    v[j] = p[j];
    m = fmaxf(m, fmaxf(fmaxf(fabsf(v[j].x), fabsf(v[j].y)), fmaxf(fabsf(v[j].z), fabsf(v[j].w))));
  }
#pragma unroll
  for (int o = 32; o; o >>= 1) m = fmaxf(m, __shfl_xor(m, o));
  if ((t & 63) == 0) wm[t >> 6] = m;
  __syncthreads();
  m = fmaxf(fmaxf(wm[0], wm[1]), fmaxf(wm[2], wm[3]));
  m = fmaxf(m, 1e-12f);
  const float inv = 127.f / m;
  union { signed char c[16]; int4 q; } o;
#pragma unroll
  for (int j = 0; j < 4; ++j) {
    o.c[j * 4 + 0] = q8(v[j].x, inv); o.c[j * 4 + 1] = q8(v[j].y, inv);
    o.c[j * 4 + 2] = q8(v[j].z, inv); o.c[j * 4 + 3] = q8(v[j].w, inv);
  }
  ((int4*)(out + (size_t)row * HH))[t] = o.q;
  if (t == 0) scale[row] = m / 127.f;
}

__global__ void quant_bf16(const unsigned short* __restrict__ in, signed char* __restrict__ out,
                           float* __restrict__ scale) {
  __shared__ float wm[4];
  const int row = blockIdx.x;
  const int t = threadIdx.x;
  const uint4* p = (const uint4*)(in + (size_t)row * HH) + t * 2;
  float f[16];
  float m = 0.f;
#pragma unroll
  for (int j = 0; j < 2; ++j) {
    uint4 d = p[j];
    unsigned u[4] = {d.x, d.y, d.z, d.w};
#pragma unroll
    for (int k = 0; k < 4; ++k) {
      f[j * 8 + k * 2] = bf2f((unsigned short)(u[k] & 0xffff));
      f[j * 8 + k * 2 + 1] = bf2f((unsigned short)(u[k] >> 16));
    }
  }
#pragma unroll
  for (int e = 0; e < 16; ++e) m = fmaxf(m, fabsf(f[e]));
#pragma unroll
  for (int o = 32; o; o >>= 1) m = fmaxf(m, __shfl_xor(m, o));
  if ((t & 63) == 0) wm[t >> 6] = m;
  __syncthreads();
  m = fmaxf(fmaxf(wm[0], wm[1]), fmaxf(wm[2], wm[3]));
  m = fmaxf(m, 1e-12f);
  const float inv = 127.f / m;
  union { signed char c[16]; int4 q; } o;
#pragma unroll
  for (int e = 0; e < 16; ++e) o.c[e] = q8(f[e], inv);
  ((int4*)(out + (size_t)row * HH))[t] = o.q;
  if (t == 0) scale[row] = m / 127.f;
}

// ---------------- split-K i8 GEMM, BK=128, XOR-swizzled staging ----------------
// 128x128 tile. 32 MFMA per barrier (2x round-5's 16). Row stride 128B = 32 banks,
// so staging XOR-swizzles the global source column (chunk ^= row&7); reads de-swizzle
// -> conflict-free ds_read_b128. LDS dest stays contiguous (global_load_lds rule).
// MODE 0: QKV (col scale from 3 concatenated regions). MODE 1: O-proj (single scale).
template <int MODE>
__global__ __launch_bounds__(256) void gemm_i8(
    const signed char* __restrict__ A, const signed char* __restrict__ W,
    const float* __restrict__ sRow,
    const float* __restrict__ s0, const float* __restrict__ s1, const float* __restrict__ s2,
    unsigned short* __restrict__ P, int N) {
  __shared__ signed char ldsA[128 * 128];
  __shared__ signed char ldsB[128 * 128];
  const int t = threadIdx.x;
  const int lane = t & 63;
  const int w = t >> 6;
  const int wr = w & 1, wc = w >> 1;
  const int l15 = lane & 15, quad = lane >> 4;
  const int bm = blockIdx.y, bn = blockIdx.x, kz = blockIdx.z;

  const int srow_ = t >> 3;                          // 0..31
  const int scol_ = ((t & 7) ^ (srow_ & 7)) * 16;    // XOR-swizzled source column
  const signed char* gA = A + (size_t)(bm * 128 + srow_) * KD + scol_ + kz * KHALF;
  const signed char* gW = W + (size_t)(bn * 128 + srow_) * KD + scol_ + kz * KHALF;
  signed char* lA = ldsA + t * 16;  // wave base + lane*16 (global_load_lds layout rule)
  signed char* lB = ldsB + t * 16;

  i32x4 acc[4][4] = {};

  for (int k0 = 0; k0 < KHALF; k0 += 128) {
    __syncthreads();
#pragma unroll
    for (int j = 0; j < 4; ++j) {
      gload_lds16(gA + (size_t)j * 32 * KD + k0, lA + j * 4096);
      gload_lds16(gW + (size_t)j * 32 * KD + k0, lB + j * 4096);
    }
    __syncthreads();
#pragma unroll
    for (int kc = 0; kc < 2; ++kc) {
      i32x4 af[4], bfr[4];
#pragma unroll
      for (int mi = 0; mi < 4; ++mi) {
        const int row = wr * 64 + mi * 16 + l15;
        const int ch = (kc * 4 + quad) ^ (row & 7);
        af[mi] = *(const i32x4*)(ldsA + row * 128 + ch * 16);
      }
#pragma unroll
      for (int ni = 0; ni < 4; ++ni) {
        const int row = wc * 64 + ni * 16 + l15;
        const int ch = (kc * 4 + quad) ^ (row & 7);
        bfr[ni] = *(const i32x4*)(ldsB + row * 128 + ch * 16);
      }
#pragma unroll
      for (int mi = 0; mi < 4; ++mi)
#pragma unroll
        for (int ni = 0; ni < 4; ++ni)
          acc[mi][ni] = MFMA_I8(af[mi], bfr[ni], acc[mi][ni]);
    }
  }

  // C/D layout: row = quad*4 + r, col = lane&15 (dtype-independent, m121-128)
  unsigned short* Pz = P + (size_t)kz * MR * N;
  const int row0 = bm * 128 + wr * 64 + quad * 4;
  const int col0 = bn * 128 + wc * 64 + l15;
#pragma unroll
  for (int ni = 0; ni < 4; ++ni) {
    const int col = col0 + ni * 16;
    float sc;
    if (MODE == 0)
      sc = (col < HH) ? s0[col] : (col < HH + KVD) ? s1[col - HH] : s2[col - HH - KVD];
    else
      sc = s0[col];
#pragma unroll
    for (int mi = 0; mi < 4; ++mi)
#pragma unroll
      for (int r = 0; r < 4; ++r) {
        const int row = row0 + mi * 16 + r;
        const float v = (float)acc[mi][ni][r] * sRow[row] * sc;
        Pz[(size_t)row * N + col] = f2h(v);
      }
  }
}

// ---------------- fused QKV epilogue: Q (bias, *1/sqrt(d)), K (bias), V (transpose) ----------------
// blocks [0,10240): Q/K cols; blocks [10240,10752): V transpose tiles.
__global__ void epi_qkv(const unsigned short* __restrict__ P0, const unsigned short* __restrict__ P1,
                        const float* __restrict__ bQ, const float* __restrict__ bK,
                        unsigned short* __restrict__ oQ, unsigned short* __restrict__ oK,
                        unsigned short* __restrict__ oVt) {
  __shared__ unsigned short lds_t[64][65];
  const int t = threadIdx.x;
  int bid = blockIdx.x;
  if (bid < 10240) {
    const int row = bid / 5;
    const int col = (bid - row * 5) * 1024 + t * 4;
    const size_t off = (size_t)row * NQKVD + col;
    float4 a = ld4h(P0 + off), b2 = ld4h(P1 + off);
    union { unsigned short s[4]; uint2 d; } o;
    if (col < HH) {
      const float4 b = *(const float4*)(bQ + col);
      o.s[0] = f2bf((a.x + b2.x + b.x) * SCALE_F);
      o.s[1] = f2bf((a.y + b2.y + b.y) * SCALE_F);
      o.s[2] = f2bf((a.z + b2.z + b.z) * SCALE_F);
      o.s[3] = f2bf((a.w + b2.w + b.w) * SCALE_F);
      *(uint2*)(oQ + (size_t)row * HH + col) = o.d;
    } else {
      const int c = col - HH;
      const float4 b = *(const float4*)(bK + c);
      o.s[0] = f2bf(a.x + b2.x + b.x); o.s[1] = f2bf(a.y + b2.y + b.y);
      o.s[2] = f2bf(a.z + b2.z + b.z); o.s[3] = f2bf(a.w + b2.w + b.w);
      *(uint2*)(oK + (size_t)row * KVD + c) = o.d;
    }
  } else {
    bid -= 10240;
    const int c0 = (bid & 15) * 64;
    const int r0 = (bid >> 4) * 64;
    const int c4 = (t & 15) * 4;
#pragma unroll
    for (int rr = 0; rr < 4; ++rr) {
      const int rl = (t >> 4) * 4 + rr;
      const size_t off = (size_t)(r0 + rl) * NQKVD + (HH + KVD) + c0 + c4;
      float4 a = ld4h(P0 + off), b = ld4h(P1 + off);
      lds_t[c4 + 0][rl] = f2bf(a.x + b.x);
      lds_t[c4 + 1][rl] = f2bf(a.y + b.y);
      lds_t[c4 + 2][rl] = f2bf(a.z + b.z);
      lds_t[c4 + 3][rl] = f2bf(a.w + b.w);
    }
    __syncthreads();
    const int cl = t >> 2;
    const int rs = (t & 3) * 16;
    union { unsigned short s[16]; uint4 q[2]; } o;
#pragma unroll
    for (int i = 0; i < 16; ++i) o.s[i] = lds_t[cl][rs + i];
    uint4* dst = (uint4*)(oVt + (size_t)(c0 + cl) * MR + r0 + rs);
    dst[0] = o.q[0]; dst[1] = o.q[1];
  }
}

__global__ void epi_o(const unsigned short* __restrict__ P0, const unsigned short* __restrict__ P1,
                      float* __restrict__ out) {
  const int col = (blockIdx.x * 256 + threadIdx.x) * 4;
  const int row = blockIdx.y;
  const size_t off = (size_t)row * HH + col;
  float4 a = ld4h(P0 + off), b = ld4h(P1 + off);
  *(float4*)(out + off) = make_float4(a.x + b.x, a.y + b.y, a.z + b.z, a.w + b.w);
}

// ---------------- flash attention: 4-wave blocks, 64-row Q tile ----------------
// Round 6 restructure (attn was 80 us @ MfmaUtil 8.7% -> stall-bound, not BW-bound):
//  * K: double-buffered LDS (2x16KB), staged one tile AHEAD (T3 2-phase recipe).
//    ONE barrier per tile (was two + full vmcnt drain); stage latency hides under
//    the whole tile's QK+softmax+PV compute.
//  * K tile stored [64][128] with XOR swizzle chunk^=(row&7), applied by
//    pre-swizzling the GLOBAL source column (gload_lds dest must stay linear,
//    rule #21). ds_read_b128 K-fragment reads: was 8-way bank conflict
//    (5.29M conflict cycles/dispatch), now 2-way = free.
//  * V: NOT staged. K/V is 4MB each = L2-resident (common-mistake #7: staging
//    L2-fit data was pure overhead, +26% measured at this exact S/D). Vt layout
//    already matches the PV B-fragment, so fragments load straight from global.
//  * LDS total unchanged: 32KB K dbuf + 11KB P = 44032B -> still 3 blocks/CU.
// Q pre-scaled by 1/sqrt(d) in epi_qkv.
__global__ __launch_bounds__(256, 3) void attn_kernel(
    const unsigned short* __restrict__ Q,   // [2048][4096]
    const unsigned short* __restrict__ K,   // [2048][1024]
    const unsigned short* __restrict__ Vt,  // [1024][2048]
    unsigned short* __restrict__ O) {       // [2048][4096]
  __shared__ unsigned short ldsK[2][64][128];  // XOR-swizzled K tiles, 32 KB
  __shared__ unsigned short ldsP[4][16 * 88];  // per-wave P tile 11 KB
  const int t = threadIdx.x;
  const int lane = t & 63;
  const int wv = t >> 6;
  const int l15 = lane & 15, quad = lane >> 4;
  const int qt = 15 - blockIdx.x;  // heavy-first
  const int h = blockIdx.y;
  const int b = blockIdx.z;
  const int kv = h >> 2;
  const int q0w = qt * 64 + wv * 16;
  const int q = q0w + l15;

  bf16x8 bq[4];
  const unsigned short* qbase = Q + (size_t)(b * SS + q0w + l15) * HH + h * HDD + quad * 8;
#pragma unroll
  for (int kk = 0; kk < 4; ++kk) bq[kk] = *(const bf16x8*)(qbase + kk * 32);

  // K staging: thread t loads rows srow+16j, source chunk pre-swizzled so that
  // linear LDS dest [row][t&15] holds global chunk (t&15)^(row&7).
  const int srow = t >> 4;                        // 0..15
  const int schunk = (t & 15) ^ (srow & 7);       // pre-swizzled source chunk
  const unsigned short* gK = K + (size_t)(b * SS + srow) * KVD + kv * HDD + schunk * 8;
  unsigned short* lp = ldsP[wv];
  // V direct-from-global fragment base (per lane)
  const unsigned short* vb = Vt + (size_t)(kv * HDD + l15) * MR + b * SS + quad * 8;

  f32x4 accO[8] = {};
  float m_run = -1e30f, l_run = 0.f;

  // prologue: stage tile 0 into buf 0 (syncthreads drains vmcnt)
#pragma unroll
  for (int j = 0; j < 4; ++j)
    gload_lds16(gK + (size_t)j * 16 * KVD, &ldsK[0][j * 16][0] + t * 8);
  __syncthreads();

  int cur = 0;
  for (int kt = 0; kt <= qt; ++kt) {
    const int k0 = kt * 64;
    // stage NEXT K tile into the other buffer; latency hidden under this
    // tile's compute, drained by the end-of-iteration barrier.
    if (kt < qt) {
#pragma unroll
      for (int j = 0; j < 4; ++j)
        gload_lds16(gK + (size_t)(k0 + 64 + j * 16) * KVD,
                    &ldsK[cur ^ 1][j * 16][0] + t * 8);
    }

    // QK^T from ldsK[cur]: de-swizzled read, conflict-free
    f32x4 st[4] = {};
#pragma unroll
    for (int kk = 0; kk < 4; ++kk)
#pragma unroll
      for (int mf = 0; mf < 4; ++mf) {
        const int r = mf * 16 + l15;
        bf16x8 af = *(const bf16x8*)(&ldsK[cur][r][((kk * 4 + quad) ^ (r & 7)) * 8]);
        st[mf] = MFMA(af, bq[kk], st[mf]);
      }

    float p[4][4];
    float cm = -1e30f;
#pragma unroll
    for (int mf = 0; mf < 4; ++mf)
#pragma unroll
      for (int r = 0; r < 4; ++r) {
        const int k = k0 + mf * 16 + quad * 4 + r;
        float v = st[mf][r];
        if (k > q) v = -1e30f;
        p[mf][r] = v;
        cm = fmaxf(cm, v);
      }
    cm = fmaxf(cm, __shfl_xor(cm, 16));
    cm = fmaxf(cm, __shfl_xor(cm, 32));
    const float mn = fmaxf(m_run, cm);
    const float al = __expf(m_run - mn);
    float sum = 0.f;
#pragma unroll
    for (int mf = 0; mf < 4; ++mf)
#pragma unroll
      for (int r = 0; r < 4; ++r) {
        const float e = __expf(p[mf][r] - mn);
        p[mf][r] = e;
        sum += e;
      }
    sum += __shfl_xor(sum, 16);
    sum += __shfl_xor(sum, 32);
    l_run = l_run * al + sum;
    m_run = mn;
    float af4[4];
#pragma unroll
    for (int r = 0; r < 4; ++r) af4[r] = __shfl(al, quad * 4 + r);
#pragma unroll
    for (int cb = 0; cb < 8; ++cb)
#pragma unroll
      for (int r = 0; r < 4; ++r) accO[cb][r] *= af4[r];

#pragma unroll
    for (int mf = 0; mf < 4; ++mf) {
      union { unsigned short s[4]; unsigned long long d; } pk;
#pragma unroll
      for (int r = 0; r < 4; ++r) pk.s[r] = f2bf(p[mf][r]);
      *(unsigned long long*)(lp + l15 * 88 + mf * 16 + quad * 4) = pk.d;
    }
    bf16x8 ap0 = *(const bf16x8*)(lp + l15 * 88 + quad * 8);
    bf16x8 ap1 = *(const bf16x8*)(lp + l15 * 88 + 32 + quad * 8);

    // PV: V fragments straight from L2-resident Vt (no LDS round-trip)
#pragma unroll
    for (int cb = 0; cb < 8; ++cb) {
      bf16x8 bv0 = *(const bf16x8*)(vb + (size_t)cb * 16 * MR + k0);
      bf16x8 bv1 = *(const bf16x8*)(vb + (size_t)cb * 16 * MR + k0 + 32);
      accO[cb] = MFMA(ap0, bv0, accO[cb]);
      accO[cb] = MFMA(ap1, bv1, accO[cb]);
    }

    // single barrier per tile: orders ldsK[cur] reads (all waves) before next
    // iteration's overwrite, and drains the stage for ldsK[cur^1].
    __syncthreads();
    cur ^= 1;
  }

  float lr[4];
#pragma unroll
  for (int r = 0; r < 4; ++r) lr[r] = __shfl(l_run, quad * 4 + r);
  unsigned short* ob = O + (size_t)(b * SS + q0w + quad * 4) * HH + h * HDD + l15;
#pragma unroll
  for (int cb = 0; cb < 8; ++cb)
#pragma unroll
    for (int r = 0; r < 4; ++r)
      ob[(size_t)r * HH + cb * 16] = f2bf(accO[cb][r] / lr[r]);
}

extern "C" void kernel_launch(void* const* d_in, const int* in_sizes, int n_in,
                              void* d_out, int out_size, void* d_ws, size_t ws_size,
                              hipStream_t stream) {
  const float* x = (const float*)d_in[0];
  const int* wq = (const int*)d_in[2];
  const float* wqs = (const float*)d_in[3];
  const float* bq = (const float*)d_in[4];
  const int* wk = (const int*)d_in[5];
  const float* wks = (const float*)d_in[6];
  const float* bk = (const float*)d_in[7];
  const int* wv = (const int*)d_in[8];
  const float* wvs = (const float*)d_in[9];
  const int* wo = (const int*)d_in[10];
  const float* wos = (const float*)d_in[11];
  float* out = (float*)d_out;
  char* ws = (char*)d_ws;

  // workspace (MiB offsets), lifetime-packed, guard 130 MiB (ws >= 136 proven round 1):
  signed char*    x_i8    = (signed char*)   (ws + (0ull   << 20)); // 8   [quant, qkv-gemm]
  signed char*    wqkv_i8 = (signed char*)   (ws + (8ull   << 20)); // 24  [cvt, qkv-gemm]
  signed char*    wo_i8   = (signed char*)   (ws + (32ull  << 20)); // 16  [cvt, o-gemm]
  unsigned short* Pq      = (unsigned short*)(ws + (48ull  << 20)); // 48  fp16 x2 [gemm, epis]
  unsigned short* q_bf    = (unsigned short*)(ws + (0ull   << 20)); // 16  [epi, attn] (over x_i8+wqkv head)
  unsigned short* k_bf    = (unsigned short*)(ws + (16ull  << 20)); // 4   [epi, attn] (over wqkv)
  unsigned short* v_t     = (unsigned short*)(ws + (20ull  << 20)); // 4   [epi, attn] (over wqkv)
  unsigned short* a_bf    = (unsigned short*)(ws + (48ull  << 20)); // 16  [attn, quant_a] (over Pq0)
  signed char*    a_i8    = (signed char*)   (ws + (64ull  << 20)); // 8   [quant_a, o-gemm] (over Pq)
  unsigned short* Po      = (unsigned short*)(ws + (96ull  << 20)); // 32  fp16 x2 [o-gemm, epi_o]
  float*          sx      = (float*)         (ws + (128ull << 20)); // 8 KB
  float*          sa      = (float*)         (ws + (129ull << 20)); // 8 KB
  if (ws_size < (130ull << 20)) return;

  quant_f32<<<MR, 256, 0, stream>>>(x, x_i8, sx);
  cvt_w_all<<<10240, 256, 0, stream>>>(wq, wk, wv, wo, wqkv_i8, wo_i8);

  gemm_i8<0><<<dim3(NQKVD / 128, MR / 128, 2), 256, 0, stream>>>(
      x_i8, wqkv_i8, sx, wqs, wks, wvs, Pq, NQKVD);

  epi_qkv<<<10752, 256, 0, stream>>>(Pq, Pq + (size_t)MR * NQKVD, bq, bk, q_bf, k_bf, v_t);

  attn_kernel<<<dim3(16, NHH, BB), 256, 0, stream>>>(q_bf, k_bf, v_t, a_bf);

  quant_bf16<<<MR, 256, 0, stream>>>(a_bf, a_i8, sa);
  gemm_i8<1><<<dim3(HH / 128, MR / 128, 2), 256, 0, stream>>>(
      a_i8, wo_i8, sa, wos, nullptr, nullptr, Po, HH);
  epi_o<<<dim3(4, MR), 256, 0, stream>>>(Po, Po + (size_t)MR * HH, out);
}

// Round 3
// 428.108 us; speedup vs baseline: 1.1625x; 1.1625x over previous
//
#include <hip/hip_runtime.h>
#include <math.h>

// Problem constants
#define BB   2
#define SS   1024
#define HH   4096
#define NHH  32
#define NKVV 8
#define HDD  128
#define MR   2048   // B*S
#define KVD  1024   // NKV*HD
#define NQKVD 6144  // H + 2*KVD
#define KD   4096
#define KHALF 2048
#define SCALE_F 0.08838834764831845f  // 1/sqrt(128)

typedef __attribute__((ext_vector_type(8))) short bf16x8;
typedef __attribute__((ext_vector_type(4))) float f32x4;
typedef __attribute__((ext_vector_type(4))) int i32x4;

#define MFMA(a, b, c) __builtin_amdgcn_mfma_f32_16x16x32_bf16((a), (b), (c), 0, 0, 0)
#define MFMA_I8(a, b, c) __builtin_amdgcn_mfma_i32_16x16x64_i8((a), (b), (c), 0, 0, 0)

__device__ __forceinline__ unsigned short f2bf(float f) {
  union { float f; unsigned u; } v; v.f = f;
  return (unsigned short)((v.u + 0x7fffu + ((v.u >> 16) & 1u)) >> 16);
}
__device__ __forceinline__ unsigned short f2h(float f) {
  union { _Float16 h; unsigned short s; } v; v.h = (_Float16)f; return v.s;
}
__device__ __forceinline__ float h2f(unsigned short s) {
  union { unsigned short s; _Float16 h; } v; v.s = s; return (float)v.h;
}
__device__ __forceinline__ float bf2f(unsigned short s) {
  union { unsigned u; float f; } v; v.u = ((unsigned)s) << 16; return v.f;
}
__device__ __forceinline__ float4 ld4h(const unsigned short* p) {
  uint2 d = *(const uint2*)p;
  float4 r;
  r.x = h2f((unsigned short)(d.x & 0xffff)); r.y = h2f((unsigned short)(d.x >> 16));
  r.z = h2f((unsigned short)(d.y & 0xffff)); r.w = h2f((unsigned short)(d.y >> 16));
  return r;
}

__device__ __forceinline__ void gload_lds16(const void* g, void* l) {
  __builtin_amdgcn_global_load_lds(
      (const __attribute__((address_space(1))) void*)g,
      (__attribute__((address_space(3))) void*)l, 16, 0, 0);
}

__device__ __forceinline__ signed char q8(float x, float inv) {
  float r = rintf(x * inv);
  r = fmaxf(-127.f, fminf(127.f, r));
  return (signed char)(int)r;
}

// ---------------- fused weight conversion: all 4 matrices, int32 -> int8 ----------------
#define NQ16 ((size_t)HH * HH / 16)
#define NK16 ((size_t)KVD * HH / 16)
__global__ void cvt_w_all(const int* __restrict__ wq, const int* __restrict__ wk,
                          const int* __restrict__ wv, const int* __restrict__ wo,
                          signed char* __restrict__ wqkv, signed char* __restrict__ wo8) {
  size_t i = (size_t)blockIdx.x * 256 + threadIdx.x;  // 16-elem chunk id
  const int* src;
  signed char* dst;
  if (i < NQ16) { src = wq; dst = wqkv; }
  else if (i < NQ16 + NK16) { src = wk - NQ16 * 16; dst = wqkv; }
  else if (i < NQ16 + 2 * NK16) { src = wv - (NQ16 + NK16) * 16; dst = wqkv; }
  else { src = wo - (NQ16 + 2 * NK16) * 16; dst = wo8 - (NQ16 + 2 * NK16) * 16; }
  const int4* p = (const int4*)(src + i * 16);
  union { signed char c[16]; int4 q; } o;
#pragma unroll
  for (int j = 0; j < 4; ++j) {
    int4 v = p[j];
    o.c[j * 4 + 0] = (signed char)v.x; o.c[j * 4 + 1] = (signed char)v.y;
    o.c[j * 4 + 2] = (signed char)v.z; o.c[j * 4 + 3] = (signed char)v.w;
  }
  *(int4*)(dst + i * 16) = o.q;
}

// ---------------- per-row quantization: one 256-thread block per row of 4096 ----------------
__global__ void quant_f32(const float* __restrict__ in, signed char* __restrict__ out,
                          float* __restrict__ scale) {
  __shared__ float wm[4];
  const int row = blockIdx.x;
  const int t = threadIdx.x;
  const float4* p = (const float4*)(in + (size_t)row * HH) + t * 4;
  float4 v[4];
  float m = 0.f;
#pragma unroll
  for (int j = 0; j < 4; ++j) {
    v[j] = p[j];
    m = fmaxf(m, fmaxf(fmaxf(fabsf(v[j].x), fabsf(v[j].y)), fmaxf(fabsf(v[j].z), fabsf(v[j].w))));
  }
#pragma unroll
  for (int o = 32; o; o >>= 1) m = fmaxf(m, __shfl_xor(m, o));
  if ((t & 63) == 0) wm[t >> 6] = m;
  __syncthreads();
  m = fmaxf(fmaxf(wm[0], wm[1]), fmaxf(wm[2], wm[3]));
  m = fmaxf(m, 1e-12f);
  const float inv = 127.f / m;
  union { signed char c[16]; int4 q; } o;
#pragma unroll
  for (int j = 0; j < 4; ++j) {
    o.c[j * 4 + 0] = q8(v[j].x, inv); o.c[j * 4 + 1] = q8(v[j].y, inv);
    o.c[j * 4 + 2] = q8(v[j].z, inv); o.c[j * 4 + 3] = q8(v[j].w, inv);
  }
  ((int4*)(out + (size_t)row * HH))[t] = o.q;
  if (t == 0) scale[row] = m / 127.f;
}

__global__ void quant_bf16(const unsigned short* __restrict__ in, signed char* __restrict__ out,
                           float* __restrict__ scale) {
  __shared__ float wm[4];
  const int row = blockIdx.x;
  const int t = threadIdx.x;
  const uint4* p = (const uint4*)(in + (size_t)row * HH) + t * 2;
  float f[16];
  float m = 0.f;
#pragma unroll
  for (int j = 0; j < 2; ++j) {
    uint4 d = p[j];
    unsigned u[4] = {d.x, d.y, d.z, d.w};
#pragma unroll
    for (int k = 0; k < 4; ++k) {
      f[j * 8 + k * 2] = bf2f((unsigned short)(u[k] & 0xffff));
      f[j * 8 + k * 2 + 1] = bf2f((unsigned short)(u[k] >> 16));
    }
  }
#pragma unroll
  for (int e = 0; e < 16; ++e) m = fmaxf(m, fabsf(f[e]));
#pragma unroll
  for (int o = 32; o; o >>= 1) m = fmaxf(m, __shfl_xor(m, o));
  if ((t & 63) == 0) wm[t >> 6] = m;
  __syncthreads();
  m = fmaxf(fmaxf(wm[0], wm[1]), fmaxf(wm[2], wm[3]));
  m = fmaxf(m, 1e-12f);
  const float inv = 127.f / m;
  union { signed char c[16]; int4 q; } o;
#pragma unroll
  for (int e = 0; e < 16; ++e) o.c[e] = q8(f[e], inv);
  ((int4*)(out + (size_t)row * HH))[t] = o.q;
  if (t == 0) scale[row] = m / 127.f;
}

// ---------------- split-K i8 GEMM, BK=128, XOR-swizzled staging ----------------
// 128x128 tile. 32 MFMA per barrier (2x round-5's 16). Row stride 128B = 32 banks,
// so staging XOR-swizzles the global source column (chunk ^= row&7); reads de-swizzle
// -> conflict-free ds_read_b128. LDS dest stays contiguous (global_load_lds rule).
// MODE 0: QKV (col scale from 3 concatenated regions). MODE 1: O-proj (single scale).
template <int MODE>
__global__ __launch_bounds__(256) void gemm_i8(
    const signed char* __restrict__ A, const signed char* __restrict__ W,
    const float* __restrict__ sRow,
    const float* __restrict__ s0, const float* __restrict__ s1, const float* __restrict__ s2,
    unsigned short* __restrict__ P, int N) {
  __shared__ signed char ldsA[128 * 128];
  __shared__ signed char ldsB[128 * 128];
  const int t = threadIdx.x;
  const int lane = t & 63;
  const int w = t >> 6;
  const int wr = w & 1, wc = w >> 1;
  const int l15 = lane & 15, quad = lane >> 4;
  const int bm = blockIdx.y, bn = blockIdx.x, kz = blockIdx.z;

  const int srow_ = t >> 3;                          // 0..31
  const int scol_ = ((t & 7) ^ (srow_ & 7)) * 16;    // XOR-swizzled source column
  const signed char* gA = A + (size_t)(bm * 128 + srow_) * KD + scol_ + kz * KHALF;
  const signed char* gW = W + (size_t)(bn * 128 + srow_) * KD + scol_ + kz * KHALF;
  signed char* lA = ldsA + t * 16;  // wave base + lane*16 (global_load_lds layout rule)
  signed char* lB = ldsB + t * 16;

  i32x4 acc[4][4] = {};

  for (int k0 = 0; k0 < KHALF; k0 += 128) {
    __syncthreads();
#pragma unroll
    for (int j = 0; j < 4; ++j) {
      gload_lds16(gA + (size_t)j * 32 * KD + k0, lA + j * 4096);
      gload_lds16(gW + (size_t)j * 32 * KD + k0, lB + j * 4096);
    }
    __syncthreads();
#pragma unroll
    for (int kc = 0; kc < 2; ++kc) {
      i32x4 af[4], bfr[4];
#pragma unroll
      for (int mi = 0; mi < 4; ++mi) {
        const int row = wr * 64 + mi * 16 + l15;
        const int ch = (kc * 4 + quad) ^ (row & 7);
        af[mi] = *(const i32x4*)(ldsA + row * 128 + ch * 16);
      }
#pragma unroll
      for (int ni = 0; ni < 4; ++ni) {
        const int row = wc * 64 + ni * 16 + l15;
        const int ch = (kc * 4 + quad) ^ (row & 7);
        bfr[ni] = *(const i32x4*)(ldsB + row * 128 + ch * 16);
      }
#pragma unroll
      for (int mi = 0; mi < 4; ++mi)
#pragma unroll
        for (int ni = 0; ni < 4; ++ni)
          acc[mi][ni] = MFMA_I8(af[mi], bfr[ni], acc[mi][ni]);
    }
  }

  // C/D layout: row = quad*4 + r, col = lane&15 (dtype-independent, m121-128)
  unsigned short* Pz = P + (size_t)kz * MR * N;
  const int row0 = bm * 128 + wr * 64 + quad * 4;
  const int col0 = bn * 128 + wc * 64 + l15;
#pragma unroll
  for (int ni = 0; ni < 4; ++ni) {
    const int col = col0 + ni * 16;
    float sc;
    if (MODE == 0)
      sc = (col < HH) ? s0[col] : (col < HH + KVD) ? s1[col - HH] : s2[col - HH - KVD];
    else
      sc = s0[col];
#pragma unroll
    for (int mi = 0; mi < 4; ++mi)
#pragma unroll
      for (int r = 0; r < 4; ++r) {
        const int row = row0 + mi * 16 + r;
        const float v = (float)acc[mi][ni][r] * sRow[row] * sc;
        Pz[(size_t)row * N + col] = f2h(v);
      }
  }
}

// ---------------- fused QKV epilogue: Q (bias, *1/sqrt(d)), K (bias), V (transpose) ----------------
// blocks [0,10240): Q/K cols; blocks [10240,10752): V transpose tiles.
__global__ void epi_qkv(const unsigned short* __restrict__ P0, const unsigned short* __restrict__ P1,
                        const float* __restrict__ bQ, const float* __restrict__ bK,
                        unsigned short* __restrict__ oQ, unsigned short* __restrict__ oK,
                        unsigned short* __restrict__ oVt) {
  __shared__ unsigned short lds_t[64][65];
  const int t = threadIdx.x;
  int bid = blockIdx.x;
  if (bid < 10240) {
    const int row = bid / 5;
    const int col = (bid - row * 5) * 1024 + t * 4;
    const size_t off = (size_t)row * NQKVD + col;
    float4 a = ld4h(P0 + off), b2 = ld4h(P1 + off);
    union { unsigned short s[4]; uint2 d; } o;
    if (col < HH) {
      const float4 b = *(const float4*)(bQ + col);
      o.s[0] = f2bf((a.x + b2.x + b.x) * SCALE_F);
      o.s[1] = f2bf((a.y + b2.y + b.y) * SCALE_F);
      o.s[2] = f2bf((a.z + b2.z + b.z) * SCALE_F);
      o.s[3] = f2bf((a.w + b2.w + b.w) * SCALE_F);
      *(uint2*)(oQ + (size_t)row * HH + col) = o.d;
    } else {
      const int c = col - HH;
      const float4 b = *(const float4*)(bK + c);
      o.s[0] = f2bf(a.x + b2.x + b.x); o.s[1] = f2bf(a.y + b2.y + b.y);
      o.s[2] = f2bf(a.z + b2.z + b.z); o.s[3] = f2bf(a.w + b2.w + b.w);
      *(uint2*)(oK + (size_t)row * KVD + c) = o.d;
    }
  } else {
    bid -= 10240;
    const int c0 = (bid & 15) * 64;
    const int r0 = (bid >> 4) * 64;
    const int c4 = (t & 15) * 4;
#pragma unroll
    for (int rr = 0; rr < 4; ++rr) {
      const int rl = (t >> 4) * 4 + rr;
      const size_t off = (size_t)(r0 + rl) * NQKVD + (HH + KVD) + c0 + c4;
      float4 a = ld4h(P0 + off), b = ld4h(P1 + off);
      lds_t[c4 + 0][rl] = f2bf(a.x + b.x);
      lds_t[c4 + 1][rl] = f2bf(a.y + b.y);
      lds_t[c4 + 2][rl] = f2bf(a.z + b.z);
      lds_t[c4 + 3][rl] = f2bf(a.w + b.w);
    }
    __syncthreads();
    const int cl = t >> 2;
    const int rs = (t & 3) * 16;
    union { unsigned short s[16]; uint4 q[2]; } o;
#pragma unroll
    for (int i = 0; i < 16; ++i) o.s[i] = lds_t[cl][rs + i];
    uint4* dst = (uint4*)(oVt + (size_t)(c0 + cl) * MR + r0 + rs);
    dst[0] = o.q[0]; dst[1] = o.q[1];
  }
}

__global__ void epi_o(const unsigned short* __restrict__ P0, const unsigned short* __restrict__ P1,
                      float* __restrict__ out) {
  const int col = (blockIdx.x * 256 + threadIdx.x) * 4;
  const int row = blockIdx.y;
  const size_t off = (size_t)row * HH + col;
  float4 a = ld4h(P0 + off), b = ld4h(P1 + off);
  *(float4*)(out + off) = make_float4(a.x + b.x, a.y + b.y, a.z + b.z, a.w + b.w);
}

// ---------------- flash attention: 4-wave blocks, 64-row Q tile ----------------
// Round 7: round-6's V-direct-from-global REGRESSED (80->142us, MfmaUtil 4.9%):
// 16 dependent 16B global loads/tile on the PV critical path, ~300cy L2 latency,
// only ~3 waves/SIMD to hide it, and each V-wait drained the K prefetch (shared
// vmcnt queue). FETCH_SIZE unchanged -> latency problem, not BW.
// This round: keep the single-barrier double-buffered pipeline (untested round-6
// theory), restore V to LDS via coalesced global_load_lds (proven round-5
// addressing) and double-buffer it too. All 12 staging loads/tile are issued a
// full tile's compute (~1500cy) ahead of the end-of-iteration __syncthreads, so
// the implicit vmcnt(0) drain waits ~0 (vs baseline: 2 barriers/tile with a full
// L2 round-trip drain each). Cost: LDS 44->75KB, occupancy 3->2 blocks/CU.
// Q pre-scaled by 1/sqrt(d) in epi_qkv.
__global__ __launch_bounds__(256, 2) void attn_kernel(
    const unsigned short* __restrict__ Q,   // [2048][4096]
    const unsigned short* __restrict__ K,   // [2048][1024]
    const unsigned short* __restrict__ Vt,  // [1024][2048]
    unsigned short* __restrict__ O) {       // [2048][4096]
  __shared__ unsigned short ldsK[2][64][128];   // K tiles (source-swizzled), 32 KB
  __shared__ unsigned short ldsV[2][2 * 128 * 32];  // V tiles [kc][hd][32], 32 KB
  __shared__ unsigned short ldsP[4][16 * 88];   // per-wave P tile 11 KB
  const int t = threadIdx.x;
  const int lane = t & 63;
  const int wv = t >> 6;
  const int l15 = lane & 15, quad = lane >> 4;
  const int qt = 15 - blockIdx.x;  // heavy-first
  const int h = blockIdx.y;
  const int b = blockIdx.z;
  const int kv = h >> 2;
  const int q0w = qt * 64 + wv * 16;
  const int q = q0w + l15;

  bf16x8 bq[4];
  const unsigned short* qbase = Q + (size_t)(b * SS + q0w + l15) * HH + h * HDD + quad * 8;
#pragma unroll
  for (int kk = 0; kk < 4; ++kk) bq[kk] = *(const bf16x8*)(qbase + kk * 32);

  // K staging: thread t loads rows srow+16j; source chunk pre-swizzled so linear
  // LDS dest [row][t&15] holds global chunk (t&15)^(row&7) (read de-swizzles).
  const int srow = t >> 4;                        // 0..15
  const int schunk = (t & 15) ^ (srow & 7);       // pre-swizzled source chunk
  const unsigned short* gK = K + (size_t)(b * SS + srow) * KVD + kv * HDD + schunk * 8;
  // V staging (proven round-5 addressing): [kc][hd 128][32 k-shorts] per tile
  const unsigned short* gV = Vt + (size_t)(kv * HDD + wv * 32 + (lane >> 2)) * MR + b * SS + (lane & 3) * 8;
  unsigned short* lV = &ldsV[0][0] + wv * 1024 + lane * 8;
  unsigned short* lp = ldsP[wv];

  f32x4 accO[8] = {};
  float m_run = -1e30f, l_run = 0.f;

  // prologue: stage tile 0 (K and V) into buf 0 (__syncthreads drains vmcnt)
#pragma unroll
  for (int j = 0; j < 4; ++j)
    gload_lds16(gK + (size_t)j * 16 * KVD, &ldsK[0][j * 16][0] + t * 8);
#pragma unroll
  for (int kc = 0; kc < 2; ++kc)
#pragma unroll
    for (int j = 0; j < 2; ++j)
      gload_lds16(gV + (size_t)j * 16 * MR + kc * 32, lV + kc * 4096 + j * 512);
  __syncthreads();

  int cur = 0;
  for (int kt = 0; kt <= qt; ++kt) {
    const int k0 = kt * 64;
    // stage NEXT tile (K and V) into the other buffers; latency hides under
    // this tile's compute, drained by the end-of-iteration barrier.
    if (kt < qt) {
#pragma unroll
      for (int j = 0; j < 4; ++j)
        gload_lds16(gK + (size_t)(k0 + 64 + j * 16) * KVD,
                    &ldsK[cur ^ 1][j * 16][0] + t * 8);
#pragma unroll
      for (int kc = 0; kc < 2; ++kc)
#pragma unroll
        for (int j = 0; j < 2; ++j)
          gload_lds16(gV + (size_t)j * 16 * MR + k0 + 64 + kc * 32,
                      lV + (cur ^ 1) * 8192 + kc * 4096 + j * 512);
    }

    // QK^T from ldsK[cur] (de-swizzled read)
    f32x4 st[4] = {};
#pragma unroll
    for (int kk = 0; kk < 4; ++kk)
#pragma unroll
      for (int mf = 0; mf < 4; ++mf) {
        const int r = mf * 16 + l15;
        bf16x8 af = *(const bf16x8*)(&ldsK[cur][r][((kk * 4 + quad) ^ (r & 7)) * 8]);
        st[mf] = MFMA(af, bq[kk], st[mf]);
      }

    float p[4][4];
    float cm = -1e30f;
#pragma unroll
    for (int mf = 0; mf < 4; ++mf)
#pragma unroll
      for (int r = 0; r < 4; ++r) {
        const int k = k0 + mf * 16 + quad * 4 + r;
        float v = st[mf][r];
        if (k > q) v = -1e30f;
        p[mf][r] = v;
        cm = fmaxf(cm, v);
      }
    cm = fmaxf(cm, __shfl_xor(cm, 16));
    cm = fmaxf(cm, __shfl_xor(cm, 32));
    const float mn = fmaxf(m_run, cm);
    const float al = __expf(m_run - mn);
    float sum = 0.f;
#pragma unroll
    for (int mf = 0; mf < 4; ++mf)
#pragma unroll
      for (int r = 0; r < 4; ++r) {
        const float e = __expf(p[mf][r] - mn);
        p[mf][r] = e;
        sum += e;
      }
    sum += __shfl_xor(sum, 16);
    sum += __shfl_xor(sum, 32);
    l_run = l_run * al + sum;
    m_run = mn;
    float af4[4];
#pragma unroll
    for (int r = 0; r < 4; ++r) af4[r] = __shfl(al, quad * 4 + r);
#pragma unroll
    for (int cb = 0; cb < 8; ++cb)
#pragma unroll
      for (int r = 0; r < 4; ++r) accO[cb][r] *= af4[r];

#pragma unroll
    for (int mf = 0; mf < 4; ++mf) {
      union { unsigned short s[4]; unsigned long long d; } pk;
#pragma unroll
      for (int r = 0; r < 4; ++r) pk.s[r] = f2bf(p[mf][r]);
      *(unsigned long long*)(lp + l15 * 88 + mf * 16 + quad * 4) = pk.d;
    }
    bf16x8 ap0 = *(const bf16x8*)(lp + l15 * 88 + quad * 8);
    bf16x8 ap1 = *(const bf16x8*)(lp + l15 * 88 + 32 + quad * 8);

    // PV from ldsV[cur]
#pragma unroll
    for (int cb = 0; cb < 8; ++cb) {
      bf16x8 bv0 = *(const bf16x8*)(&ldsV[cur][0] + (cb * 16 + l15) * 32 + quad * 8);
      bf16x8 bv1 = *(const bf16x8*)(&ldsV[cur][0] + 4096 + (cb * 16 + l15) * 32 + quad * 8);
      accO[cb] = MFMA(ap0, bv0, accO[cb]);
      accO[cb] = MFMA(ap1, bv1, accO[cb]);
    }

    // single barrier per tile: orders this tile's LDS reads (all waves) before
    // the next iteration's overwrite, and drains the prefetch (already landed).
    __syncthreads();
    cur ^= 1;
  }

  float lr[4];
#pragma unroll
  for (int r = 0; r < 4; ++r) lr[r] = __shfl(l_run, quad * 4 + r);
  unsigned short* ob = O + (size_t)(b * SS + q0w + quad * 4) * HH + h * HDD + l15;
#pragma unroll
  for (int cb = 0; cb < 8; ++cb)
#pragma unroll
    for (int r = 0; r < 4; ++r)
      ob[(size_t)r * HH + cb * 16] = f2bf(accO[cb][r] / lr[r]);
}

extern "C" void kernel_launch(void* const* d_in, const int* in_sizes, int n_in,
                              void* d_out, int out_size, void* d_ws, size_t ws_size,
                              hipStream_t stream) {
  const float* x = (const float*)d_in[0];
  const int* wq = (const int*)d_in[2];
  const float* wqs = (const float*)d_in[3];
  const float* bq = (const float*)d_in[4];
  const int* wk = (const int*)d_in[5];
  const float* wks = (const float*)d_in[6];
  const float* bk = (const float*)d_in[7];
  const int* wv = (const int*)d_in[8];
  const float* wvs = (const float*)d_in[9];
  const int* wo = (const int*)d_in[10];
  const float* wos = (const float*)d_in[11];
  float* out = (float*)d_out;
  char* ws = (char*)d_ws;

  // workspace (MiB offsets), lifetime-packed, guard 130 MiB (ws >= 136 proven round 1):
  signed char*    x_i8    = (signed char*)   (ws + (0ull   << 20)); // 8   [quant, qkv-gemm]
  signed char*    wqkv_i8 = (signed char*)   (ws + (8ull   << 20)); // 24  [cvt, qkv-gemm]
  signed char*    wo_i8   = (signed char*)   (ws + (32ull  << 20)); // 16  [cvt, o-gemm]
  unsigned short* Pq      = (unsigned short*)(ws + (48ull  << 20)); // 48  fp16 x2 [gemm, epis]
  unsigned short* q_bf    = (unsigned short*)(ws + (0ull   << 20)); // 16  [epi, attn] (over x_i8+wqkv head)
  unsigned short* k_bf    = (unsigned short*)(ws + (16ull  << 20)); // 4   [epi, attn] (over wqkv)
  unsigned short* v_t     = (unsigned short*)(ws + (20ull  << 20)); // 4   [epi, attn] (over wqkv)
  unsigned short* a_bf    = (unsigned short*)(ws + (48ull  << 20)); // 16  [attn, quant_a] (over Pq0)
  signed char*    a_i8    = (signed char*)   (ws + (64ull  << 20)); // 8   [quant_a, o-gemm] (over Pq)
  unsigned short* Po      = (unsigned short*)(ws + (96ull  << 20)); // 32  fp16 x2 [o-gemm, epi_o]
  float*          sx      = (float*)         (ws + (128ull << 20)); // 8 KB
  float*          sa      = (float*)         (ws + (129ull << 20)); // 8 KB
  if (ws_size < (130ull << 20)) return;

  quant_f32<<<MR, 256, 0, stream>>>(x, x_i8, sx);
  cvt_w_all<<<10240, 256, 0, stream>>>(wq, wk, wv, wo, wqkv_i8, wo_i8);

  gemm_i8<0><<<dim3(NQKVD / 128, MR / 128, 2), 256, 0, stream>>>(
      x_i8, wqkv_i8, sx, wqs, wks, wvs, Pq, NQKVD);

  epi_qkv<<<10752, 256, 0, stream>>>(Pq, Pq + (size_t)MR * NQKVD, bq, bk, q_bf, k_bf, v_t);

  attn_kernel<<<dim3(16, NHH, BB), 256, 0, stream>>>(q_bf, k_bf, v_t, a_bf);

  quant_bf16<<<MR, 256, 0, stream>>>(a_bf, a_i8, sa);
  gemm_i8<1><<<dim3(HH / 128, MR / 128, 2), 256, 0, stream>>>(
      a_i8, wo_i8, sa, wos, nullptr, nullptr, Po, HH);
  epi_o<<<dim3(4, MR), 256, 0, stream>>>(Po, Po + (size_t)MR * HH, out);
}

// Round 4
// 424.796 us; speedup vs baseline: 1.1715x; 1.0078x over previous
//
#include <hip/hip_runtime.h>
#include <math.h>

// Problem constants
#define BB   2
#define SS   1024
#define HH   4096
#define NHH  32
#define NKVV 8
#define HDD  128
#define MR   2048   // B*S
#define KVD  1024   // NKV*HD
#define NQKVD 6144  // H + 2*KVD
#define KD   4096
#define KHALF 2048
// 1/sqrt(128) * log2(e): attention scores produced directly in exp2 domain
#define SCALE2_F 0.12751744f

typedef __attribute__((ext_vector_type(8))) short bf16x8;
typedef __attribute__((ext_vector_type(4))) float f32x4;
typedef __attribute__((ext_vector_type(4))) int i32x4;

#define MFMA(a, b, c) __builtin_amdgcn_mfma_f32_16x16x32_bf16((a), (b), (c), 0, 0, 0)
#define MFMA_I8(a, b, c) __builtin_amdgcn_mfma_i32_16x16x64_i8((a), (b), (c), 0, 0, 0)

__device__ __forceinline__ unsigned short f2bf(float f) {
  union { float f; unsigned u; } v; v.f = f;
  return (unsigned short)((v.u + 0x7fffu + ((v.u >> 16) & 1u)) >> 16);
}
__device__ __forceinline__ unsigned short f2h(float f) {
  union { _Float16 h; unsigned short s; } v; v.h = (_Float16)f; return v.s;
}
__device__ __forceinline__ float h2f(unsigned short s) {
  union { unsigned short s; _Float16 h; } v; v.s = s; return (float)v.h;
}
__device__ __forceinline__ float bf2f(unsigned short s) {
  union { unsigned u; float f; } v; v.u = ((unsigned)s) << 16; return v.f;
}
__device__ __forceinline__ float4 ld4h(const unsigned short* p) {
  uint2 d = *(const uint2*)p;
  float4 r;
  r.x = h2f((unsigned short)(d.x & 0xffff)); r.y = h2f((unsigned short)(d.x >> 16));
  r.z = h2f((unsigned short)(d.y & 0xffff)); r.w = h2f((unsigned short)(d.y >> 16));
  return r;
}
// 2^x via the hardware transcendental (v_exp_f32 IS exp2)
__device__ __forceinline__ float exp2_fast(float x) {
  float r; asm("v_exp_f32 %0, %1" : "=v"(r) : "v"(x)); return r;
}
// pack two f32 -> packed bf16 pair (lo = s0, hi = s1), single instruction
__device__ __forceinline__ unsigned cvt_pk_bf16(float a, float b) {
  unsigned r; asm("v_cvt_pk_bf16_f32 %0, %1, %2" : "=v"(r) : "v"(a), "v"(b)); return r;
}

__device__ __forceinline__ void gload_lds16(const void* g, void* l) {
  __builtin_amdgcn_global_load_lds(
      (const __attribute__((address_space(1))) void*)g,
      (__attribute__((address_space(3))) void*)l, 16, 0, 0);
}

__device__ __forceinline__ signed char q8(float x, float inv) {
  float r = rintf(x * inv);
  r = fmaxf(-127.f, fminf(127.f, r));
  return (signed char)(int)r;
}

// ---------------- fused weight conversion: all 4 matrices, int32 -> int8 ----------------
#define NQ16 ((size_t)HH * HH / 16)
#define NK16 ((size_t)KVD * HH / 16)
__global__ void cvt_w_all(const int* __restrict__ wq, const int* __restrict__ wk,
                          const int* __restrict__ wv, const int* __restrict__ wo,
                          signed char* __restrict__ wqkv, signed char* __restrict__ wo8) {
  size_t i = (size_t)blockIdx.x * 256 + threadIdx.x;  // 16-elem chunk id
  const int* src;
  signed char* dst;
  if (i < NQ16) { src = wq; dst = wqkv; }
  else if (i < NQ16 + NK16) { src = wk - NQ16 * 16; dst = wqkv; }
  else if (i < NQ16 + 2 * NK16) { src = wv - (NQ16 + NK16) * 16; dst = wqkv; }
  else { src = wo - (NQ16 + 2 * NK16) * 16; dst = wo8 - (NQ16 + 2 * NK16) * 16; }
  const int4* p = (const int4*)(src + i * 16);
  union { signed char c[16]; int4 q; } o;
#pragma unroll
  for (int j = 0; j < 4; ++j) {
    int4 v = p[j];
    o.c[j * 4 + 0] = (signed char)v.x; o.c[j * 4 + 1] = (signed char)v.y;
    o.c[j * 4 + 2] = (signed char)v.z; o.c[j * 4 + 3] = (signed char)v.w;
  }
  *(int4*)(dst + i * 16) = o.q;
}

// ---------------- per-row quantization: one 256-thread block per row of 4096 ----------------
__global__ void quant_f32(const float* __restrict__ in, signed char* __restrict__ out,
                          float* __restrict__ scale) {
  __shared__ float wm[4];
  const int row = blockIdx.x;
  const int t = threadIdx.x;
  const float4* p = (const float4*)(in + (size_t)row * HH) + t * 4;
  float4 v[4];
  float m = 0.f;
#pragma unroll
  for (int j = 0; j < 4; ++j) {
    v[j] = p[j];
    m = fmaxf(m, fmaxf(fmaxf(fabsf(v[j].x), fabsf(v[j].y)), fmaxf(fabsf(v[j].z), fabsf(v[j].w))));
  }
#pragma unroll
  for (int o = 32; o; o >>= 1) m = fmaxf(m, __shfl_xor(m, o));
  if ((t & 63) == 0) wm[t >> 6] = m;
  __syncthreads();
  m = fmaxf(fmaxf(wm[0], wm[1]), fmaxf(wm[2], wm[3]));
  m = fmaxf(m, 1e-12f);
  const float inv = 127.f / m;
  union { signed char c[16]; int4 q; } o;
#pragma unroll
  for (int j = 0; j < 4; ++j) {
    o.c[j * 4 + 0] = q8(v[j].x, inv); o.c[j * 4 + 1] = q8(v[j].y, inv);
    o.c[j * 4 + 2] = q8(v[j].z, inv); o.c[j * 4 + 3] = q8(v[j].w, inv);
  }
  ((int4*)(out + (size_t)row * HH))[t] = o.q;
  if (t == 0) scale[row] = m / 127.f;
}

__global__ void quant_bf16(const unsigned short* __restrict__ in, signed char* __restrict__ out,
                           float* __restrict__ scale) {
  __shared__ float wm[4];
  const int row = blockIdx.x;
  const int t = threadIdx.x;
  const uint4* p = (const uint4*)(in + (size_t)row * HH) + t * 2;
  float f[16];
  float m = 0.f;
#pragma unroll
  for (int j = 0; j < 2; ++j) {
    uint4 d = p[j];
    unsigned u[4] = {d.x, d.y, d.z, d.w};
#pragma unroll
    for (int k = 0; k < 4; ++k) {
      f[j * 8 + k * 2] = bf2f((unsigned short)(u[k] & 0xffff));
      f[j * 8 + k * 2 + 1] = bf2f((unsigned short)(u[k] >> 16));
    }
  }
#pragma unroll
  for (int e = 0; e < 16; ++e) m = fmaxf(m, fabsf(f[e]));
#pragma unroll
  for (int o = 32; o; o >>= 1) m = fmaxf(m, __shfl_xor(m, o));
  if ((t & 63) == 0) wm[t >> 6] = m;
  __syncthreads();
  m = fmaxf(fmaxf(wm[0], wm[1]), fmaxf(wm[2], wm[3]));
  m = fmaxf(m, 1e-12f);
  const float inv = 127.f / m;
  union { signed char c[16]; int4 q; } o;
#pragma unroll
  for (int e = 0; e < 16; ++e) o.c[e] = q8(f[e], inv);
  ((int4*)(out + (size_t)row * HH))[t] = o.q;
  if (t == 0) scale[row] = m / 127.f;
}

// ---------------- split-K i8 GEMM, BK=128, XOR-swizzled staging ----------------
template <int MODE>
__global__ __launch_bounds__(256) void gemm_i8(
    const signed char* __restrict__ A, const signed char* __restrict__ W,
    const float* __restrict__ sRow,
    const float* __restrict__ s0, const float* __restrict__ s1, const float* __restrict__ s2,
    unsigned short* __restrict__ P, int N) {
  __shared__ signed char ldsA[128 * 128];
  __shared__ signed char ldsB[128 * 128];
  const int t = threadIdx.x;
  const int lane = t & 63;
  const int w = t >> 6;
  const int wr = w & 1, wc = w >> 1;
  const int l15 = lane & 15, quad = lane >> 4;
  const int bm = blockIdx.y, bn = blockIdx.x, kz = blockIdx.z;

  const int srow_ = t >> 3;                          // 0..31
  const int scol_ = ((t & 7) ^ (srow_ & 7)) * 16;    // XOR-swizzled source column
  const signed char* gA = A + (size_t)(bm * 128 + srow_) * KD + scol_ + kz * KHALF;
  const signed char* gW = W + (size_t)(bn * 128 + srow_) * KD + scol_ + kz * KHALF;
  signed char* lA = ldsA + t * 16;  // wave base + lane*16 (global_load_lds layout rule)
  signed char* lB = ldsB + t * 16;

  i32x4 acc[4][4] = {};

  for (int k0 = 0; k0 < KHALF; k0 += 128) {
    __syncthreads();
#pragma unroll
    for (int j = 0; j < 4; ++j) {
      gload_lds16(gA + (size_t)j * 32 * KD + k0, lA + j * 4096);
      gload_lds16(gW + (size_t)j * 32 * KD + k0, lB + j * 4096);
    }
    __syncthreads();
#pragma unroll
    for (int kc = 0; kc < 2; ++kc) {
      i32x4 af[4], bfr[4];
#pragma unroll
      for (int mi = 0; mi < 4; ++mi) {
        const int row = wr * 64 + mi * 16 + l15;
        const int ch = (kc * 4 + quad) ^ (row & 7);
        af[mi] = *(const i32x4*)(ldsA + row * 128 + ch * 16);
      }
#pragma unroll
      for (int ni = 0; ni < 4; ++ni) {
        const int row = wc * 64 + ni * 16 + l15;
        const int ch = (kc * 4 + quad) ^ (row & 7);
        bfr[ni] = *(const i32x4*)(ldsB + row * 128 + ch * 16);
      }
#pragma unroll
      for (int mi = 0; mi < 4; ++mi)
#pragma unroll
        for (int ni = 0; ni < 4; ++ni)
          acc[mi][ni] = MFMA_I8(af[mi], bfr[ni], acc[mi][ni]);
    }
  }

  // C/D layout: row = quad*4 + r, col = lane&15 (dtype-independent, m121-128)
  unsigned short* Pz = P + (size_t)kz * MR * N;
  const int row0 = bm * 128 + wr * 64 + quad * 4;
  const int col0 = bn * 128 + wc * 64 + l15;
#pragma unroll
  for (int ni = 0; ni < 4; ++ni) {
    const int col = col0 + ni * 16;
    float sc;
    if (MODE == 0)
      sc = (col < HH) ? s0[col] : (col < HH + KVD) ? s1[col - HH] : s2[col - HH - KVD];
    else
      sc = s0[col];
#pragma unroll
    for (int mi = 0; mi < 4; ++mi)
#pragma unroll
      for (int r = 0; r < 4; ++r) {
        const int row = row0 + mi * 16 + r;
        const float v = (float)acc[mi][ni][r] * sRow[row] * sc;
        Pz[(size_t)row * N + col] = f2h(v);
      }
  }
}

// ---------------- fused QKV epilogue: Q (bias, *log2e/sqrt(d)), K (bias), V (transpose) ----
__global__ void epi_qkv(const unsigned short* __restrict__ P0, const unsigned short* __restrict__ P1,
                        const float* __restrict__ bQ, const float* __restrict__ bK,
                        unsigned short* __restrict__ oQ, unsigned short* __restrict__ oK,
                        unsigned short* __restrict__ oVt) {
  __shared__ unsigned short lds_t[64][65];
  const int t = threadIdx.x;
  int bid = blockIdx.x;
  if (bid < 10240) {
    const int row = bid / 5;
    const int col = (bid - row * 5) * 1024 + t * 4;
    const size_t off = (size_t)row * NQKVD + col;
    float4 a = ld4h(P0 + off), b2 = ld4h(P1 + off);
    union { unsigned short s[4]; uint2 d; } o;
    if (col < HH) {
      const float4 b = *(const float4*)(bQ + col);
      o.s[0] = f2bf((a.x + b2.x + b.x) * SCALE2_F);
      o.s[1] = f2bf((a.y + b2.y + b.y) * SCALE2_F);
      o.s[2] = f2bf((a.z + b2.z + b.z) * SCALE2_F);
      o.s[3] = f2bf((a.w + b2.w + b.w) * SCALE2_F);
      *(uint2*)(oQ + (size_t)row * HH + col) = o.d;
    } else {
      const int c = col - HH;
      const float4 b = *(const float4*)(bK + c);
      o.s[0] = f2bf(a.x + b2.x + b.x); o.s[1] = f2bf(a.y + b2.y + b.y);
      o.s[2] = f2bf(a.z + b2.z + b.z); o.s[3] = f2bf(a.w + b2.w + b.w);
      *(uint2*)(oK + (size_t)row * KVD + c) = o.d;
    }
  } else {
    bid -= 10240;
    const int c0 = (bid & 15) * 64;
    const int r0 = (bid >> 4) * 64;
    const int c4 = (t & 15) * 4;
#pragma unroll
    for (int rr = 0; rr < 4; ++rr) {
      const int rl = (t >> 4) * 4 + rr;
      const size_t off = (size_t)(r0 + rl) * NQKVD + (HH + KVD) + c0 + c4;
      float4 a = ld4h(P0 + off), b = ld4h(P1 + off);
      lds_t[c4 + 0][rl] = f2bf(a.x + b.x);
      lds_t[c4 + 1][rl] = f2bf(a.y + b.y);
      lds_t[c4 + 2][rl] = f2bf(a.z + b.z);
      lds_t[c4 + 3][rl] = f2bf(a.w + b.w);
    }
    __syncthreads();
    const int cl = t >> 2;
    const int rs = (t & 3) * 16;
    union { unsigned short s[16]; uint4 q[2]; } o;
#pragma unroll
    for (int i = 0; i < 16; ++i) o.s[i] = lds_t[cl][rs + i];
    uint4* dst = (uint4*)(oVt + (size_t)(c0 + cl) * MR + r0 + rs);
    dst[0] = o.q[0]; dst[1] = o.q[1];
  }
}

__global__ void epi_o(const unsigned short* __restrict__ P0, const unsigned short* __restrict__ P1,
                      float* __restrict__ out) {
  const int col = (blockIdx.x * 256 + threadIdx.x) * 4;
  const int row = blockIdx.y;
  const size_t off = (size_t)row * HH + col;
  float4 a = ld4h(P0 + off), b = ld4h(P1 + off);
  *(float4*)(out + off) = make_float4(a.x + b.x, a.y + b.y, a.z + b.z, a.w + b.w);
}

// ---------------- flash attention: 4-wave blocks, 64-row Q tile ----------------
// Round 8: round-3 showed the barrier-drain was NOT dominant (1-barrier dbuf
// pipeline: 80.4->78.5us only). VALUBusy:MfmaUtil = 23:8.7 with both <25% ->
// softmax VALU dependency chain dominates (~500 VALU insts/tile/wave, mostly
// the ~80-op hand f2bf pack + mask + exp + rescale). This round cuts the chain:
//  * v_cvt_pk_bf16_f32: 8 insts replace ~80 for P->bf16 pack (T12 primitive)
//  * exp2 domain: log2e folded into Q pre-scale (epi_qkv), raw v_exp_f32
//  * causal mask applied ONLY on the diagonal tile (kt==qt)
//  * defer-max THR=8 (T13): skip al/broadcast/rescale when max doesn't grow
//  * lane-local l accumulation: sum-reduce shuffles once at end, not per tile
//  * s_setprio(1) around MFMA clusters (T5, +4-7% attn in m191)
// Q pre-scaled by log2e/sqrt(d) in epi_qkv; scores are exp2-domain.
__global__ __launch_bounds__(256, 2) void attn_kernel(
    const unsigned short* __restrict__ Q,   // [2048][4096]
    const unsigned short* __restrict__ K,   // [2048][1024]
    const unsigned short* __restrict__ Vt,  // [1024][2048]
    unsigned short* __restrict__ O) {       // [2048][4096]
  __shared__ unsigned short ldsK[2][64][128];   // K tiles (source-swizzled), 32 KB
  __shared__ unsigned short ldsV[2][2 * 128 * 32];  // V tiles [kc][hd][32], 32 KB
  __shared__ unsigned short ldsP[4][16 * 88];   // per-wave P tile 11 KB
  const int t = threadIdx.x;
  const int lane = t & 63;
  const int wv = t >> 6;
  const int l15 = lane & 15, quad = lane >> 4;
  const int qt = 15 - blockIdx.x;  // heavy-first
  const int h = blockIdx.y;
  const int b = blockIdx.z;
  const int kv = h >> 2;
  const int q0w = qt * 64 + wv * 16;
  const int q = q0w + l15;

  bf16x8 bq[4];
  const unsigned short* qbase = Q + (size_t)(b * SS + q0w + l15) * HH + h * HDD + quad * 8;
#pragma unroll
  for (int kk = 0; kk < 4; ++kk) bq[kk] = *(const bf16x8*)(qbase + kk * 32);

  const int srow = t >> 4;                        // 0..15
  const int schunk = (t & 15) ^ (srow & 7);       // pre-swizzled source chunk
  const unsigned short* gK = K + (size_t)(b * SS + srow) * KVD + kv * HDD + schunk * 8;
  const unsigned short* gV = Vt + (size_t)(kv * HDD + wv * 32 + (lane >> 2)) * MR + b * SS + (lane & 3) * 8;
  unsigned short* lV = &ldsV[0][0] + wv * 1024 + lane * 8;
  unsigned short* lp = ldsP[wv];

  f32x4 accO[8] = {};
  float m_run = -1e30f, l_part = 0.f;

  // prologue: stage tile 0 (K and V) into buf 0 (__syncthreads drains vmcnt)
#pragma unroll
  for (int j = 0; j < 4; ++j)
    gload_lds16(gK + (size_t)j * 16 * KVD, &ldsK[0][j * 16][0] + t * 8);
#pragma unroll
  for (int kc = 0; kc < 2; ++kc)
#pragma unroll
    for (int j = 0; j < 2; ++j)
      gload_lds16(gV + (size_t)j * 16 * MR + kc * 32, lV + kc * 4096 + j * 512);
  __syncthreads();

  int cur = 0;
  for (int kt = 0; kt <= qt; ++kt) {
    const int k0 = kt * 64;
    // prefetch NEXT tile (K and V) into the other buffers
    if (kt < qt) {
#pragma unroll
      for (int j = 0; j < 4; ++j)
        gload_lds16(gK + (size_t)(k0 + 64 + j * 16) * KVD,
                    &ldsK[cur ^ 1][j * 16][0] + t * 8);
#pragma unroll
      for (int kc = 0; kc < 2; ++kc)
#pragma unroll
        for (int j = 0; j < 2; ++j)
          gload_lds16(gV + (size_t)j * 16 * MR + k0 + 64 + kc * 32,
                      lV + (cur ^ 1) * 8192 + kc * 4096 + j * 512);
    }

    // QK^T from ldsK[cur] (de-swizzled read)
    f32x4 st[4] = {};
    __builtin_amdgcn_s_setprio(1);
#pragma unroll
    for (int kk = 0; kk < 4; ++kk)
#pragma unroll
      for (int mf = 0; mf < 4; ++mf) {
        const int r = mf * 16 + l15;
        bf16x8 af = *(const bf16x8*)(&ldsK[cur][r][((kk * 4 + quad) ^ (r & 7)) * 8]);
        st[mf] = MFMA(af, bq[kk], st[mf]);
      }
    __builtin_amdgcn_s_setprio(0);

    float p[4][4];
#pragma unroll
    for (int mf = 0; mf < 4; ++mf)
#pragma unroll
      for (int r = 0; r < 4; ++r) p[mf][r] = st[mf][r];
    if (kt == qt) {  // causal mask only on the diagonal tile
#pragma unroll
      for (int mf = 0; mf < 4; ++mf)
#pragma unroll
        for (int r = 0; r < 4; ++r) {
          const int k = k0 + mf * 16 + quad * 4 + r;
          if (k > q) p[mf][r] = -1e30f;
        }
    }
    float cm = -1e30f;
#pragma unroll
    for (int mf = 0; mf < 4; ++mf)
#pragma unroll
      for (int r = 0; r < 4; ++r) cm = fmaxf(cm, p[mf][r]);
    cm = fmaxf(cm, __shfl_xor(cm, 16));
    cm = fmaxf(cm, __shfl_xor(cm, 32));

    // defer-max (T13): rescale only when some row's max grew past THR=8
    if (!__all(cm <= m_run + 8.f)) {
      const float mn = fmaxf(m_run, cm);
      const float al = exp2_fast(m_run - mn);
      l_part *= al;
      m_run = mn;
      float af4[4];
#pragma unroll
      for (int r = 0; r < 4; ++r) af4[r] = __shfl(al, quad * 4 + r);
#pragma unroll
      for (int cb = 0; cb < 8; ++cb)
#pragma unroll
        for (int r = 0; r < 4; ++r) accO[cb][r] *= af4[r];
    }

    // exp2 + lane-local l + cvt_pk pack (8 insts, was ~80)
#pragma unroll
    for (int mf = 0; mf < 4; ++mf) {
      const float e0 = exp2_fast(p[mf][0] - m_run);
      const float e1 = exp2_fast(p[mf][1] - m_run);
      const float e2 = exp2_fast(p[mf][2] - m_run);
      const float e3 = exp2_fast(p[mf][3] - m_run);
      l_part += (e0 + e1) + (e2 + e3);
      union { unsigned u[2]; unsigned long long d; } pk;
      pk.u[0] = cvt_pk_bf16(e0, e1);
      pk.u[1] = cvt_pk_bf16(e2, e3);
      *(unsigned long long*)(lp + l15 * 88 + mf * 16 + quad * 4) = pk.d;
    }
    bf16x8 ap0 = *(const bf16x8*)(lp + l15 * 88 + quad * 8);
    bf16x8 ap1 = *(const bf16x8*)(lp + l15 * 88 + 32 + quad * 8);

    // PV from ldsV[cur]
    __builtin_amdgcn_s_setprio(1);
#pragma unroll
    for (int cb = 0; cb < 8; ++cb) {
      bf16x8 bv0 = *(const bf16x8*)(&ldsV[cur][0] + (cb * 16 + l15) * 32 + quad * 8);
      bf16x8 bv1 = *(const bf16x8*)(&ldsV[cur][0] + 4096 + (cb * 16 + l15) * 32 + quad * 8);
      accO[cb] = MFMA(ap0, bv0, accO[cb]);
      accO[cb] = MFMA(ap1, bv1, accO[cb]);
    }
    __builtin_amdgcn_s_setprio(0);

    __syncthreads();
    cur ^= 1;
  }

  // final l reduce (once, not per tile)
  l_part += __shfl_xor(l_part, 16);
  l_part += __shfl_xor(l_part, 32);
  float lr[4];
#pragma unroll
  for (int r = 0; r < 4; ++r) lr[r] = __shfl(l_part, quad * 4 + r);
  unsigned short* ob = O + (size_t)(b * SS + q0w + quad * 4) * HH + h * HDD + l15;
#pragma unroll
  for (int cb = 0; cb < 8; ++cb)
#pragma unroll
    for (int r = 0; r < 4; ++r)
      ob[(size_t)r * HH + cb * 16] = f2bf(accO[cb][r] / lr[r]);
}

extern "C" void kernel_launch(void* const* d_in, const int* in_sizes, int n_in,
                              void* d_out, int out_size, void* d_ws, size_t ws_size,
                              hipStream_t stream) {
  const float* x = (const float*)d_in[0];
  const int* wq = (const int*)d_in[2];
  const float* wqs = (const float*)d_in[3];
  const float* bq = (const float*)d_in[4];
  const int* wk = (const int*)d_in[5];
  const float* wks = (const float*)d_in[6];
  const float* bk = (const float*)d_in[7];
  const int* wv = (const int*)d_in[8];
  const float* wvs = (const float*)d_in[9];
  const int* wo = (const int*)d_in[10];
  const float* wos = (const float*)d_in[11];
  float* out = (float*)d_out;
  char* ws = (char*)d_ws;

  // workspace (MiB offsets), lifetime-packed, guard 130 MiB (ws >= 136 proven round 1):
  signed char*    x_i8    = (signed char*)   (ws + (0ull   << 20)); // 8   [quant, qkv-gemm]
  signed char*    wqkv_i8 = (signed char*)   (ws + (8ull   << 20)); // 24  [cvt, qkv-gemm]
  signed char*    wo_i8   = (signed char*)   (ws + (32ull  << 20)); // 16  [cvt, o-gemm]
  unsigned short* Pq      = (unsigned short*)(ws + (48ull  << 20)); // 48  fp16 x2 [gemm, epis]
  unsigned short* q_bf    = (unsigned short*)(ws + (0ull   << 20)); // 16  [epi, attn] (over x_i8+wqkv head)
  unsigned short* k_bf    = (unsigned short*)(ws + (16ull  << 20)); // 4   [epi, attn] (over wqkv)
  unsigned short* v_t     = (unsigned short*)(ws + (20ull  << 20)); // 4   [epi, attn] (over wqkv)
  unsigned short* a_bf    = (unsigned short*)(ws + (48ull  << 20)); // 16  [attn, quant_a] (over Pq0)
  signed char*    a_i8    = (signed char*)   (ws + (64ull  << 20)); // 8   [quant_a, o-gemm] (over Pq)
  unsigned short* Po      = (unsigned short*)(ws + (96ull  << 20)); // 32  fp16 x2 [o-gemm, epi_o]
  float*          sx      = (float*)         (ws + (128ull << 20)); // 8 KB
  float*          sa      = (float*)         (ws + (129ull << 20)); // 8 KB
  if (ws_size < (130ull << 20)) return;

  quant_f32<<<MR, 256, 0, stream>>>(x, x_i8, sx);
  cvt_w_all<<<10240, 256, 0, stream>>>(wq, wk, wv, wo, wqkv_i8, wo_i8);

  gemm_i8<0><<<dim3(NQKVD / 128, MR / 128, 2), 256, 0, stream>>>(
      x_i8, wqkv_i8, sx, wqs, wks, wvs, Pq, NQKVD);

  epi_qkv<<<10752, 256, 0, stream>>>(Pq, Pq + (size_t)MR * NQKVD, bq, bk, q_bf, k_bf, v_t);

  attn_kernel<<<dim3(16, NHH, BB), 256, 0, stream>>>(q_bf, k_bf, v_t, a_bf);

  quant_bf16<<<MR, 256, 0, stream>>>(a_bf, a_i8, sa);
  gemm_i8<1><<<dim3(HH / 128, MR / 128, 2), 256, 0, stream>>>(
      a_i8, wo_i8, sa, wos, nullptr, nullptr, Po, HH);
  epi_o<<<dim3(4, MR), 256, 0, stream>>>(Po, Po + (size_t)MR * HH, out);
}

// Round 5
// 398.848 us; speedup vs baseline: 1.2478x; 1.0651x over previous
//
#include <hip/hip_runtime.h>
#include <math.h>

// Problem constants
#define BB   2
#define SS   1024
#define HH   4096
#define NHH  32
#define NKVV 8
#define HDD  128
#define MR   2048   // B*S
#define KVD  1024   // NKV*HD
#define NQKVD 6144  // H + 2*KVD
#define KD   4096
// 1/sqrt(128) * log2(e): attention scores produced directly in exp2 domain
#define SCALE2_F 0.12751744f

typedef __attribute__((ext_vector_type(8))) short bf16x8;
typedef __attribute__((ext_vector_type(4))) float f32x4;
typedef __attribute__((ext_vector_type(4))) int i32x4;

#define MFMA(a, b, c) __builtin_amdgcn_mfma_f32_16x16x32_bf16((a), (b), (c), 0, 0, 0)
#define MFMA_I8(a, b, c) __builtin_amdgcn_mfma_i32_16x16x64_i8((a), (b), (c), 0, 0, 0)

__device__ __forceinline__ unsigned short f2bf(float f) {
  union { float f; unsigned u; } v; v.f = f;
  return (unsigned short)((v.u + 0x7fffu + ((v.u >> 16) & 1u)) >> 16);
}
__device__ __forceinline__ float bf2f(unsigned short s) {
  union { unsigned u; float f; } v; v.u = ((unsigned)s) << 16; return v.f;
}
// 2^x via the hardware transcendental (v_exp_f32 IS exp2)
__device__ __forceinline__ float exp2_fast(float x) {
  float r; asm("v_exp_f32 %0, %1" : "=v"(r) : "v"(x)); return r;
}
// pack two f32 -> packed bf16 pair (lo = s0, hi = s1), single instruction
__device__ __forceinline__ unsigned cvt_pk_bf16(float a, float b) {
  unsigned r; asm("v_cvt_pk_bf16_f32 %0, %1, %2" : "=v"(r) : "v"(a), "v"(b)); return r;
}

__device__ __forceinline__ void gload_lds16(const void* g, void* l) {
  __builtin_amdgcn_global_load_lds(
      (const __attribute__((address_space(1))) void*)g,
      (__attribute__((address_space(3))) void*)l, 16, 0, 0);
}

__device__ __forceinline__ signed char q8(float x, float inv) {
  float r = rintf(x * inv);
  r = fmaxf(-127.f, fminf(127.f, r));
  return (signed char)(int)r;
}

// ---------------- fused weight conversion: all 4 matrices, int32 -> int8 ----------------
#define NQ16 ((size_t)HH * HH / 16)
#define NK16 ((size_t)KVD * HH / 16)
__global__ void cvt_w_all(const int* __restrict__ wq, const int* __restrict__ wk,
                          const int* __restrict__ wv, const int* __restrict__ wo,
                          signed char* __restrict__ wqkv, signed char* __restrict__ wo8) {
  size_t i = (size_t)blockIdx.x * 256 + threadIdx.x;  // 16-elem chunk id
  const int* src;
  signed char* dst;
  if (i < NQ16) { src = wq; dst = wqkv; }
  else if (i < NQ16 + NK16) { src = wk - NQ16 * 16; dst = wqkv; }
  else if (i < NQ16 + 2 * NK16) { src = wv - (NQ16 + NK16) * 16; dst = wqkv; }
  else { src = wo - (NQ16 + 2 * NK16) * 16; dst = wo8 - (NQ16 + 2 * NK16) * 16; }
  const int4* p = (const int4*)(src + i * 16);
  union { signed char c[16]; int4 q; } o;
#pragma unroll
  for (int j = 0; j < 4; ++j) {
    int4 v = p[j];
    o.c[j * 4 + 0] = (signed char)v.x; o.c[j * 4 + 1] = (signed char)v.y;
    o.c[j * 4 + 2] = (signed char)v.z; o.c[j * 4 + 3] = (signed char)v.w;
  }
  *(int4*)(dst + i * 16) = o.q;
}

// ---------------- per-row quantization: one 256-thread block per row of 4096 ----------------
__global__ void quant_f32(const float* __restrict__ in, signed char* __restrict__ out,
                          float* __restrict__ scale) {
  __shared__ float wm[4];
  const int row = blockIdx.x;
  const int t = threadIdx.x;
  const float4* p = (const float4*)(in + (size_t)row * HH) + t * 4;
  float4 v[4];
  float m = 0.f;
#pragma unroll
  for (int j = 0; j < 4; ++j) {
    v[j] = p[j];
    m = fmaxf(m, fmaxf(fmaxf(fabsf(v[j].x), fabsf(v[j].y)), fmaxf(fabsf(v[j].z), fabsf(v[j].w))));
  }
#pragma unroll
  for (int o = 32; o; o >>= 1) m = fmaxf(m, __shfl_xor(m, o));
  if ((t & 63) == 0) wm[t >> 6] = m;
  __syncthreads();
  m = fmaxf(fmaxf(wm[0], wm[1]), fmaxf(wm[2], wm[3]));
  m = fmaxf(m, 1e-12f);
  const float inv = 127.f / m;
  union { signed char c[16]; int4 q; } o;
#pragma unroll
  for (int j = 0; j < 4; ++j) {
    o.c[j * 4 + 0] = q8(v[j].x, inv); o.c[j * 4 + 1] = q8(v[j].y, inv);
    o.c[j * 4 + 2] = q8(v[j].z, inv); o.c[j * 4 + 3] = q8(v[j].w, inv);
  }
  ((int4*)(out + (size_t)row * HH))[t] = o.q;
  if (t == 0) scale[row] = m / 127.f;
}

__global__ void quant_bf16(const unsigned short* __restrict__ in, signed char* __restrict__ out,
                           float* __restrict__ scale) {
  __shared__ float wm[4];
  const int row = blockIdx.x;
  const int t = threadIdx.x;
  const uint4* p = (const uint4*)(in + (size_t)row * HH) + t * 2;
  float f[16];
  float m = 0.f;
#pragma unroll
  for (int j = 0; j < 2; ++j) {
    uint4 d = p[j];
    unsigned u[4] = {d.x, d.y, d.z, d.w};
#pragma unroll
    for (int k = 0; k < 4; ++k) {
      f[j * 8 + k * 2] = bf2f((unsigned short)(u[k] & 0xffff));
      f[j * 8 + k * 2 + 1] = bf2f((unsigned short)(u[k] >> 16));
    }
  }
#pragma unroll
  for (int e = 0; e < 16; ++e) m = fmaxf(m, fabsf(f[e]));
#pragma unroll
  for (int o = 32; o; o >>= 1) m = fmaxf(m, __shfl_xor(m, o));
  if ((t & 63) == 0) wm[t >> 6] = m;
  __syncthreads();
  m = fmaxf(fmaxf(wm[0], wm[1]), fmaxf(wm[2], wm[3]));
  m = fmaxf(m, 1e-12f);
  const float inv = 127.f / m;
  union { signed char c[16]; int4 q; } o;
#pragma unroll
  for (int e = 0; e < 16; ++e) o.c[e] = q8(f[e], inv);
  ((int4*)(out + (size_t)row * HH))[t] = o.q;
  if (t == 0) scale[row] = m / 127.f;
}

// ---------------- i8 GEMM, full-K, fused epilogue (round 9: split-K removed) ----------------
// Round-4 counters: QKV gemm WRITE_SIZE 51 MB (split-K fp16 partials) + epi_qkv
// re-read/re-write = pure HBM overhead. Dropping split-K lets the epilogue write
// FINAL outputs directly: Q (bias+scale bf16), K (bias bf16), V (transposed 8B
// stores into Vt), O-proj (f32 out). Pq/Po buffers and both epi kernels deleted.
// 128x128 tile, BK=128, XOR-swizzled staging (source column chunk ^= row&7,
// LDS dest linear per global_load_lds rule; reads de-swizzle -> conflict-free).
// MODE 0: QKV fused epilogue. MODE 1: O-proj f32 epilogue.
template <int MODE>
__global__ __launch_bounds__(256) void gemm_i8(
    const signed char* __restrict__ A, const signed char* __restrict__ W,
    const float* __restrict__ sRow,
    const float* __restrict__ s0, const float* __restrict__ s1, const float* __restrict__ s2,
    const float* __restrict__ bQ, const float* __restrict__ bK,
    unsigned short* __restrict__ oQ, unsigned short* __restrict__ oK,
    unsigned short* __restrict__ oVt, float* __restrict__ oF) {
  __shared__ signed char ldsA[128 * 128];
  __shared__ signed char ldsB[128 * 128];
  const int t = threadIdx.x;
  const int lane = t & 63;
  const int w = t >> 6;
  const int wr = w & 1, wc = w >> 1;
  const int l15 = lane & 15, quad = lane >> 4;
  const int bm = blockIdx.y, bn = blockIdx.x;

  const int srow_ = t >> 3;                          // 0..31
  const int scol_ = ((t & 7) ^ (srow_ & 7)) * 16;    // XOR-swizzled source column
  const signed char* gA = A + (size_t)(bm * 128 + srow_) * KD + scol_;
  const signed char* gW = W + (size_t)(bn * 128 + srow_) * KD + scol_;
  signed char* lA = ldsA + t * 16;  // wave base + lane*16 (global_load_lds layout rule)
  signed char* lB = ldsB + t * 16;

  i32x4 acc[4][4] = {};

  for (int k0 = 0; k0 < KD; k0 += 128) {
    __syncthreads();
#pragma unroll
    for (int j = 0; j < 4; ++j) {
      gload_lds16(gA + (size_t)j * 32 * KD + k0, lA + j * 4096);
      gload_lds16(gW + (size_t)j * 32 * KD + k0, lB + j * 4096);
    }
    __syncthreads();
#pragma unroll
    for (int kc = 0; kc < 2; ++kc) {
      i32x4 af[4], bfr[4];
#pragma unroll
      for (int mi = 0; mi < 4; ++mi) {
        const int row = wr * 64 + mi * 16 + l15;
        const int ch = (kc * 4 + quad) ^ (row & 7);
        af[mi] = *(const i32x4*)(ldsA + row * 128 + ch * 16);
      }
#pragma unroll
      for (int ni = 0; ni < 4; ++ni) {
        const int row = wc * 64 + ni * 16 + l15;
        const int ch = (kc * 4 + quad) ^ (row & 7);
        bfr[ni] = *(const i32x4*)(ldsB + row * 128 + ch * 16);
      }
#pragma unroll
      for (int mi = 0; mi < 4; ++mi)
#pragma unroll
        for (int ni = 0; ni < 4; ++ni)
          acc[mi][ni] = MFMA_I8(af[mi], bfr[ni], acc[mi][ni]);
    }
  }

  // C/D layout: row = quad*4 + r, col = lane&15 (dtype-independent, m121-128)
  const int row0 = bm * 128 + wr * 64 + quad * 4;
  const int col0 = bn * 128 + wc * 64 + l15;
  if (MODE == 1) {
    // O-projection: write f32 final output directly
#pragma unroll
    for (int ni = 0; ni < 4; ++ni) {
      const int col = col0 + ni * 16;
      const float sc = s0[col];
#pragma unroll
      for (int mi = 0; mi < 4; ++mi)
#pragma unroll
        for (int r = 0; r < 4; ++r) {
          const int row = row0 + mi * 16 + r;
          oF[(size_t)row * HH + col] = (float)acc[mi][ni][r] * sRow[row] * sc;
        }
    }
  } else if (col0 < HH) {
    // Q region: (v + bias) * log2e/sqrt(d), bf16 (exp2-domain pre-scale)
#pragma unroll
    for (int ni = 0; ni < 4; ++ni) {
      const int col = col0 + ni * 16;
      const float sc = s0[col];
      const float bv = bQ[col];
#pragma unroll
      for (int mi = 0; mi < 4; ++mi)
#pragma unroll
        for (int r = 0; r < 4; ++r) {
          const int row = row0 + mi * 16 + r;
          oQ[(size_t)row * HH + col] =
              f2bf(((float)acc[mi][ni][r] * sRow[row] * sc + bv) * SCALE2_F);
        }
    }
  } else if (col0 < HH + KVD) {
    // K region: + bias, bf16
#pragma unroll
    for (int ni = 0; ni < 4; ++ni) {
      const int col = col0 + ni * 16;
      const float sc = s1[col - HH];
      const float bv = bK[col - HH];
#pragma unroll
      for (int mi = 0; mi < 4; ++mi)
#pragma unroll
        for (int r = 0; r < 4; ++r) {
          const int row = row0 + mi * 16 + r;
          oK[(size_t)row * KVD + (col - HH)] =
              f2bf((float)acc[mi][ni][r] * sRow[row] * sc + bv);
        }
    }
  } else {
    // V region: write TRANSPOSED into Vt[col][row]; lane's 4 r-rows are
    // consecutive -> one 8B store per (mi,ni) fragment.
#pragma unroll
    for (int ni = 0; ni < 4; ++ni) {
      const int c = col0 + ni * 16 - (HH + KVD);
      const float sc = s2[c];
#pragma unroll
      for (int mi = 0; mi < 4; ++mi) {
        union { unsigned short s[4]; unsigned long long d; } pk;
#pragma unroll
        for (int r = 0; r < 4; ++r) {
          const int row = row0 + mi * 16 + r;
          pk.s[r] = f2bf((float)acc[mi][ni][r] * sRow[row] * sc);
        }
        *(unsigned long long*)(oVt + (size_t)c * MR + row0 + mi * 16) = pk.d;
      }
    }
  }
}

// ---------------- flash attention: 4-wave blocks, 64-row Q tile ----------------
// Round-4 verified: softmax chain cuts (cvt_pk pack, exp2 domain, diagonal-only
// mask, defer-max THR=8, lane-local l, setprio) dropped attn out of the top-5
// (<69us from 78.5). Structure: single-barrier double-buffered K+V LDS pipeline.
// Q pre-scaled by log2e/sqrt(d) in the QKV gemm epilogue; scores are exp2-domain.
__global__ __launch_bounds__(256, 2) void attn_kernel(
    const unsigned short* __restrict__ Q,   // [2048][4096]
    const unsigned short* __restrict__ K,   // [2048][1024]
    const unsigned short* __restrict__ Vt,  // [1024][2048]
    unsigned short* __restrict__ O) {       // [2048][4096]
  __shared__ unsigned short ldsK[2][64][128];   // K tiles (source-swizzled), 32 KB
  __shared__ unsigned short ldsV[2][2 * 128 * 32];  // V tiles [kc][hd][32], 32 KB
  __shared__ unsigned short ldsP[4][16 * 88];   // per-wave P tile 11 KB
  const int t = threadIdx.x;
  const int lane = t & 63;
  const int wv = t >> 6;
  const int l15 = lane & 15, quad = lane >> 4;
  const int qt = 15 - blockIdx.x;  // heavy-first
  const int h = blockIdx.y;
  const int b = blockIdx.z;
  const int kv = h >> 2;
  const int q0w = qt * 64 + wv * 16;
  const int q = q0w + l15;

  bf16x8 bq[4];
  const unsigned short* qbase = Q + (size_t)(b * SS + q0w + l15) * HH + h * HDD + quad * 8;
#pragma unroll
  for (int kk = 0; kk < 4; ++kk) bq[kk] = *(const bf16x8*)(qbase + kk * 32);

  const int srow = t >> 4;                        // 0..15
  const int schunk = (t & 15) ^ (srow & 7);       // pre-swizzled source chunk
  const unsigned short* gK = K + (size_t)(b * SS + srow) * KVD + kv * HDD + schunk * 8;
  const unsigned short* gV = Vt + (size_t)(kv * HDD + wv * 32 + (lane >> 2)) * MR + b * SS + (lane & 3) * 8;
  unsigned short* lV = &ldsV[0][0] + wv * 1024 + lane * 8;
  unsigned short* lp = ldsP[wv];

  f32x4 accO[8] = {};
  float m_run = -1e30f, l_part = 0.f;

  // prologue: stage tile 0 (K and V) into buf 0 (__syncthreads drains vmcnt)
#pragma unroll
  for (int j = 0; j < 4; ++j)
    gload_lds16(gK + (size_t)j * 16 * KVD, &ldsK[0][j * 16][0] + t * 8);
#pragma unroll
  for (int kc = 0; kc < 2; ++kc)
#pragma unroll
    for (int j = 0; j < 2; ++j)
      gload_lds16(gV + (size_t)j * 16 * MR + kc * 32, lV + kc * 4096 + j * 512);
  __syncthreads();

  int cur = 0;
  for (int kt = 0; kt <= qt; ++kt) {
    const int k0 = kt * 64;
    // prefetch NEXT tile (K and V) into the other buffers
    if (kt < qt) {
#pragma unroll
      for (int j = 0; j < 4; ++j)
        gload_lds16(gK + (size_t)(k0 + 64 + j * 16) * KVD,
                    &ldsK[cur ^ 1][j * 16][0] + t * 8);
#pragma unroll
      for (int kc = 0; kc < 2; ++kc)
#pragma unroll
        for (int j = 0; j < 2; ++j)
          gload_lds16(gV + (size_t)j * 16 * MR + k0 + 64 + kc * 32,
                      lV + (cur ^ 1) * 8192 + kc * 4096 + j * 512);
    }

    // QK^T from ldsK[cur] (de-swizzled read)
    f32x4 st[4] = {};
    __builtin_amdgcn_s_setprio(1);
#pragma unroll
    for (int kk = 0; kk < 4; ++kk)
#pragma unroll
      for (int mf = 0; mf < 4; ++mf) {
        const int r = mf * 16 + l15;
        bf16x8 af = *(const bf16x8*)(&ldsK[cur][r][((kk * 4 + quad) ^ (r & 7)) * 8]);
        st[mf] = MFMA(af, bq[kk], st[mf]);
      }
    __builtin_amdgcn_s_setprio(0);

    float p[4][4];
#pragma unroll
    for (int mf = 0; mf < 4; ++mf)
#pragma unroll
      for (int r = 0; r < 4; ++r) p[mf][r] = st[mf][r];
    if (kt == qt) {  // causal mask only on the diagonal tile
#pragma unroll
      for (int mf = 0; mf < 4; ++mf)
#pragma unroll
        for (int r = 0; r < 4; ++r) {
          const int k = k0 + mf * 16 + quad * 4 + r;
          if (k > q) p[mf][r] = -1e30f;
        }
    }
    float cm = -1e30f;
#pragma unroll
    for (int mf = 0; mf < 4; ++mf)
#pragma unroll
      for (int r = 0; r < 4; ++r) cm = fmaxf(cm, p[mf][r]);
    cm = fmaxf(cm, __shfl_xor(cm, 16));
    cm = fmaxf(cm, __shfl_xor(cm, 32));

    // defer-max (T13): rescale only when some row's max grew past THR=8
    if (!__all(cm <= m_run + 8.f)) {
      const float mn = fmaxf(m_run, cm);
      const float al = exp2_fast(m_run - mn);
      l_part *= al;
      m_run = mn;
      float af4[4];
#pragma unroll
      for (int r = 0; r < 4; ++r) af4[r] = __shfl(al, quad * 4 + r);
#pragma unroll
      for (int cb = 0; cb < 8; ++cb)
#pragma unroll
        for (int r = 0; r < 4; ++r) accO[cb][r] *= af4[r];
    }

    // exp2 + lane-local l + cvt_pk pack (8 insts, was ~80)
#pragma unroll
    for (int mf = 0; mf < 4; ++mf) {
      const float e0 = exp2_fast(p[mf][0] - m_run);
      const float e1 = exp2_fast(p[mf][1] - m_run);
      const float e2 = exp2_fast(p[mf][2] - m_run);
      const float e3 = exp2_fast(p[mf][3] - m_run);
      l_part += (e0 + e1) + (e2 + e3);
      union { unsigned u[2]; unsigned long long d; } pk;
      pk.u[0] = cvt_pk_bf16(e0, e1);
      pk.u[1] = cvt_pk_bf16(e2, e3);
      *(unsigned long long*)(lp + l15 * 88 + mf * 16 + quad * 4) = pk.d;
    }
    bf16x8 ap0 = *(const bf16x8*)(lp + l15 * 88 + quad * 8);
    bf16x8 ap1 = *(const bf16x8*)(lp + l15 * 88 + 32 + quad * 8);

    // PV from ldsV[cur]
    __builtin_amdgcn_s_setprio(1);
#pragma unroll
    for (int cb = 0; cb < 8; ++cb) {
      bf16x8 bv0 = *(const bf16x8*)(&ldsV[cur][0] + (cb * 16 + l15) * 32 + quad * 8);
      bf16x8 bv1 = *(const bf16x8*)(&ldsV[cur][0] + 4096 + (cb * 16 + l15) * 32 + quad * 8);
      accO[cb] = MFMA(ap0, bv0, accO[cb]);
      accO[cb] = MFMA(ap1, bv1, accO[cb]);
    }
    __builtin_amdgcn_s_setprio(0);

    __syncthreads();
    cur ^= 1;
  }

  // final l reduce (once, not per tile)
  l_part += __shfl_xor(l_part, 16);
  l_part += __shfl_xor(l_part, 32);
  float lr[4];
#pragma unroll
  for (int r = 0; r < 4; ++r) lr[r] = __shfl(l_part, quad * 4 + r);
  unsigned short* ob = O + (size_t)(b * SS + q0w + quad * 4) * HH + h * HDD + l15;
#pragma unroll
  for (int cb = 0; cb < 8; ++cb)
#pragma unroll
    for (int r = 0; r < 4; ++r)
      ob[(size_t)r * HH + cb * 16] = f2bf(accO[cb][r] / lr[r]);
}

extern "C" void kernel_launch(void* const* d_in, const int* in_sizes, int n_in,
                              void* d_out, int out_size, void* d_ws, size_t ws_size,
                              hipStream_t stream) {
  const float* x = (const float*)d_in[0];
  const int* wq = (const int*)d_in[2];
  const float* wqs = (const float*)d_in[3];
  const float* bq = (const float*)d_in[4];
  const int* wk = (const int*)d_in[5];
  const float* wks = (const float*)d_in[6];
  const float* bk = (const float*)d_in[7];
  const int* wv = (const int*)d_in[8];
  const float* wvs = (const float*)d_in[9];
  const int* wo = (const int*)d_in[10];
  const float* wos = (const float*)d_in[11];
  float* out = (float*)d_out;
  char* ws = (char*)d_ws;

  // workspace (MiB offsets), now overlap-free (split-K P buffers deleted):
  signed char*    x_i8    = (signed char*)   (ws + (0ull   << 20)); // 8   [quant, qkv-gemm]
  signed char*    wqkv_i8 = (signed char*)   (ws + (8ull   << 20)); // 24  [cvt, qkv-gemm]
  signed char*    wo_i8   = (signed char*)   (ws + (32ull  << 20)); // 16  [cvt, o-gemm]
  unsigned short* q_bf    = (unsigned short*)(ws + (48ull  << 20)); // 16  [qkv-gemm, attn]
  unsigned short* k_bf    = (unsigned short*)(ws + (64ull  << 20)); // 4   [qkv-gemm, attn]
  unsigned short* v_t     = (unsigned short*)(ws + (68ull  << 20)); // 4   [qkv-gemm, attn]
  unsigned short* a_bf    = (unsigned short*)(ws + (72ull  << 20)); // 16  [attn, quant_a]
  signed char*    a_i8    = (signed char*)   (ws + (88ull  << 20)); // 8   [quant_a, o-gemm]
  float*          sx      = (float*)         (ws + (128ull << 20)); // 8 KB
  float*          sa      = (float*)         (ws + (129ull << 20)); // 8 KB
  if (ws_size < (130ull << 20)) return;

  quant_f32<<<MR, 256, 0, stream>>>(x, x_i8, sx);
  cvt_w_all<<<10240, 256, 0, stream>>>(wq, wk, wv, wo, wqkv_i8, wo_i8);

  // QKV GEMM, full-K, fused epilogue -> q_bf / k_bf / v_t directly
  gemm_i8<0><<<dim3(NQKVD / 128, MR / 128), 256, 0, stream>>>(
      x_i8, wqkv_i8, sx, wqs, wks, wvs, bq, bk, q_bf, k_bf, v_t, nullptr);

  attn_kernel<<<dim3(16, NHH, BB), 256, 0, stream>>>(q_bf, k_bf, v_t, a_bf);

  quant_bf16<<<MR, 256, 0, stream>>>(a_bf, a_i8, sa);

  // O GEMM, full-K, writes final f32 output directly
  gemm_i8<1><<<dim3(HH / 128, MR / 128), 256, 0, stream>>>(
      a_i8, wo_i8, sa, wos, nullptr, nullptr, nullptr, nullptr,
      nullptr, nullptr, nullptr, out);
}